// Round 7
// baseline (121.748 us; speedup 1.0000x reference)
//
#include <hip/hip_runtime.h>
#include <hip/hip_bf16.h>

#define NF     128
#define BATCH  64
#define NNODES 4096
#define MROWS  (BATCH * NNODES)       // 262144
#define NEDGE  (BATCH * (NNODES - 1)) // 262080
#define LN_EPS 1e-5f

typedef short  short8  __attribute__((ext_vector_type(8)));
typedef float  float4v __attribute__((ext_vector_type(4)));

__device__ __forceinline__ unsigned short f2bf(float f) {
    union { float f; unsigned u; } v; v.f = f;
    unsigned r = v.u;
    r = r + 0x7FFF + ((r >> 16) & 1);   // RNE
    return (unsigned short)(r >> 16);
}
__device__ __forceinline__ float bf2f(unsigned short b) {
    union { unsigned u; float f; } v; v.u = ((unsigned)b) << 16;
    return v.f;
}
// packed f32x2 -> bf16x2 (v_cvt_pk_bf16_f32), low short = lo. RNE == f2bf.
__device__ __forceinline__ unsigned pkbf(float lo, float hi) {
    __hip_bfloat162 h = __float22bfloat162_rn(float2{lo, hi});
    union { __hip_bfloat162 h; unsigned u; } v; v.h = h;
    return v.u;
}
// 8 fp32 -> one A-fragment octet (short8 of bf16); layout verified in r7/r12.
__device__ __forceinline__ short8 packfrag(float4v a, float4v b) {
    union { short8 s; unsigned u[4]; } v;
    v.u[0] = pkbf(a[0], a[1]); v.u[1] = pkbf(a[2], a[3]);
    v.u[2] = pkbf(b[0], b[1]); v.u[3] = pkbf(b[2], b[3]);
    return v.s;
}

// DPP 16-lane sum (VALU pipe, no LDS). Exact for aligned 16-lane groups.
template <int CTRL>
__device__ __forceinline__ float dppadd(float v) {
    union { float f; int i; } a, b; a.f = v;
    b.i = __builtin_amdgcn_mov_dpp(a.i, CTRL, 0xF, 0xF, true);
    return v + b.f;
}
__device__ __forceinline__ float red16(float v) {
    v = dppadd<0xB1>(v);    // quad_perm ^1
    v = dppadd<0x4E>(v);    // quad_perm ^2
    v = dppadd<0x141>(v);   // row_half_mirror (== ^4 after quad-uniform)
    v = dppadd<0x140>(v);   // row_mirror      (== ^8 after half-uniform)
    return v;
}

// A-fragment slot address (shorts): slot(q,m) holds A[m][k-octet q] (16 B).
// XOR swizzle spreads bank groups (validated r4-r6).
__device__ __forceinline__ int slotAddr(int q, int m) {
    return ((q * 16 + m) ^ (q & 7)) * 8;
}

// Stage W (128x128 fp32, k-major) into WF in bf16 MFMA B-fragment order.
// PERM: k-row k is placed at fragment position p=(k&15)*8+(k>>4), matching the
// permuted feature layout n(p)=(p&7)*16+(p>>3) used for h1-slots and h2.
// NT = block size in threads (generic strided loop).
template <bool PERM, int NT>
__device__ __forceinline__ void stage_wfrags(const float* __restrict__ W,
                                             unsigned short* __restrict__ WF,
                                             int tid) {
    for (int g = tid; g < 4096; g += NT) {
        int k  = g >> 5;                  // true input-feature row 0..127
        int n0 = (g & 31) * 4;
        float4v wv = *(const float4v*)(W + k * NF + n0);
        int p = PERM ? ((k & 15) * 8 + (k >> 4)) : k;
        int s = p >> 5, q = (p & 31) >> 3, j = p & 7;
        #pragma unroll
        for (int e = 0; e < 4; ++e) {
            int n = n0 + e;
            WF[((((n >> 4) * 4 + s) * 64) + q * 16 + (n & 15)) * 8 + j] = f2bf(wv[e]);
        }
    }
}

// bias + LayerNorm(128) + ELU on C-layout accumulators (r6-verified form).
__device__ __forceinline__ void ln_elu(float4v acc[8], const float* __restrict__ PI,
                                       int lnm) {
    float bias[8], gn[8], bt[8];
    #pragma unroll
    for (int c = 0; c < 8; ++c) {
        float4v prm = *(const float4v*)&PI[(c * 16 + lnm) * 4];
        bias[c] = prm[0]; gn[c] = prm[1]; bt[c] = prm[2];
    }
    #pragma unroll
    for (int r = 0; r < 4; ++r) {
        float s1 = 0.f, s2 = 0.f;
        #pragma unroll
        for (int c = 0; c < 8; ++c) {
            float t = acc[c][r] + bias[c];
            acc[c][r] = t;
            s1 += t; s2 += t * t;
        }
        s1 = red16(s1);
        s2 = red16(s2);
        float mu  = s1 * (1.0f / 128.0f);
        float var = s2 * (1.0f / 128.0f) - mu * mu;
        float rs  = rsqrtf(var + LN_EPS);
        #pragma unroll
        for (int c = 0; c < 8; ++c) {
            float y = (acc[c][r] - mu) * rs * gn[c] + bt[c];
            acc[c][r] = (y > 0.f) ? y : (__expf(y) - 1.0f);
        }
    }
}

// r13: dual-strip variant — SAME per-element ops/order as ln_elu on each acc
// set; only the param loads are shared. Two independent dpp-reduce chains
// interleave in the scheduler (the ILP this round is about).
__device__ __forceinline__ void ln_elu2(float4v a[8], float4v b[8],
                                        const float* __restrict__ PI, int lnm) {
    float bias[8], gn[8], bt[8];
    #pragma unroll
    for (int c = 0; c < 8; ++c) {
        float4v prm = *(const float4v*)&PI[(c * 16 + lnm) * 4];
        bias[c] = prm[0]; gn[c] = prm[1]; bt[c] = prm[2];
    }
    #pragma unroll
    for (int r = 0; r < 4; ++r) {
        float s1a = 0.f, s2a = 0.f, s1b = 0.f, s2b = 0.f;
        #pragma unroll
        for (int c = 0; c < 8; ++c) {
            float ta = a[c][r] + bias[c];
            a[c][r] = ta; s1a += ta; s2a += ta * ta;
            float tb = b[c][r] + bias[c];
            b[c][r] = tb; s1b += tb; s2b += tb * tb;
        }
        s1a = red16(s1a); s2a = red16(s2a);
        s1b = red16(s1b); s2b = red16(s2b);
        float mua = s1a * (1.0f / 128.0f);
        float vara = s2a * (1.0f / 128.0f) - mua * mua;
        float rsa = rsqrtf(vara + LN_EPS);
        float mub = s1b * (1.0f / 128.0f);
        float varb = s2b * (1.0f / 128.0f) - mub * mub;
        float rsb = rsqrtf(varb + LN_EPS);
        #pragma unroll
        for (int c = 0; c < 8; ++c) {
            float ya = (a[c][r] - mua) * rsa * gn[c] + bt[c];
            a[c][r] = (ya > 0.f) ? ya : (__expf(ya) - 1.0f);
            float yb = (b[c][r] - mub) * rsb * gn[c] + bt[c];
            b[c][r] = (yb > 0.f) ? yb : (__expf(yb) - 1.0f);
        }
    }
}

// ---------------- fused layer1+layer2 ----------------
// r13: 512 threads (8 waves, r10 config), TWO strips per wave (ILP).
// LDS carve (shorts): WF1 [0,16384) | WF2 [16384,32768) |
//   MYF [32768, 32768+8*4096) | PI (floats) at 65536: 2 sets x 512 floats
#define F_MYF   32768
#define F_PI    65536
#define F_TOT   (65536 + 2048)          // shorts -> 135168 B

// History: 1024/4 -> 128-VGPR clamp -> spills (WRITE 122-155 MB). 512/2
// (r10) -> zero spill, 78-80 us. 768/3 (r11) regressed. r12 (A-from-global)
// neutral -> x-stage LDS wasn't critical. Profile stuck at Mfma 8 / VALU 40
// / Occ 18: latency-bound inside each wave, registers abundant (88/256).
// r13: dual-strip ILP — two independent chains per wave; every WF B-read
// feeds 2 MFMAs; LN params amortize; strips 2p/2p+1 contiguous in memory.
__global__ __launch_bounds__(512, 2)
void fused12_kernel(const float* __restrict__ x,
                    const float* __restrict__ W1, const float* __restrict__ b1,
                    const float* __restrict__ g1, const float* __restrict__ be1,
                    const float* __restrict__ W2, const float* __restrict__ b2,
                    const float* __restrict__ g2, const float* __restrict__ be2,
                    unsigned short* __restrict__ h2out)
{
    __shared__ __align__(16) unsigned short SH[F_TOT];

    const int tid  = threadIdx.x;
    const int lane = tid & 63;
    const int wave = tid >> 6;        // 0..7
    const int lnm  = lane & 15;
    const int qu   = lane >> 4;

    stage_wfrags<false, 512>(W1, &SH[0], tid);
    stage_wfrags<true , 512>(W2, &SH[16384], tid);
    float* PIf = (float*)&SH[F_PI];
    if (tid < NF) {
        PIf[tid * 4 + 0] = b1[tid]; PIf[tid * 4 + 1] = g1[tid]; PIf[tid * 4 + 2] = be1[tid];
        PIf[512 + tid * 4 + 0] = b2[tid]; PIf[512 + tid * 4 + 1] = g2[tid];
        PIf[512 + tid * 4 + 2] = be2[tid];
    }

    unsigned short* myFA = &SH[F_MYF + wave * 4096];
    unsigned short* myFB = myFA + 2048;
    const unsigned short* WF1 = &SH[0];
    const unsigned short* WF2 = &SH[16384];

    const int npairs = MROWS / 32;           // 8192 pairs of strips
    const int pstep  = gridDim.x * 8;        // 2048
    int pair = blockIdx.x * 8 + wave;

    // fragment-order x loads (r12-verified): lane (qu,lnm) reads row lnm,
    // float octet s*4+qu of each strip.
    const int laneOff = lnm * NF + qu * 8;

    float4v xfA[8], xfB[8];
    short8  afcA[4], afcB[4];
    if (pair < npairs) {
        const float* xrA = x + (size_t)(2 * pair)     * (16 * NF) + laneOff;
        const float* xrB = x + (size_t)(2 * pair + 1) * (16 * NF) + laneOff;
        #pragma unroll
        for (int s = 0; s < 4; ++s) {
            xfA[2 * s]     = *(const float4v*)(xrA + s * 32);
            xfA[2 * s + 1] = *(const float4v*)(xrA + s * 32 + 4);
            xfB[2 * s]     = *(const float4v*)(xrB + s * 32);
            xfB[2 * s + 1] = *(const float4v*)(xrB + s * 32 + 4);
        }
        #pragma unroll
        for (int s = 0; s < 4; ++s) {
            afcA[s] = packfrag(xfA[2 * s], xfA[2 * s + 1]);
            afcB[s] = packfrag(xfB[2 * s], xfB[2 * s + 1]);
        }
    }
    __syncthreads();

    for (; pair < npairs; pair += pstep) {
        // issue next pair's loads first: in flight through layer1 + LN1
        int pn = pair + pstep;
        if (pn < npairs) {
            const float* xrA = x + (size_t)(2 * pn)     * (16 * NF) + laneOff;
            const float* xrB = x + (size_t)(2 * pn + 1) * (16 * NF) + laneOff;
            #pragma unroll
            for (int s = 0; s < 4; ++s) {
                xfA[2 * s]     = *(const float4v*)(xrA + s * 32);
                xfA[2 * s + 1] = *(const float4v*)(xrA + s * 32 + 4);
                xfB[2 * s]     = *(const float4v*)(xrB + s * 32);
                xfB[2 * s + 1] = *(const float4v*)(xrB + s * 32 + 4);
            }
        }

        // layer 1 MFMA: A from registers, each B-fragment read feeds 2 MFMAs
        float4v accA[8], accB[8];
        #pragma unroll
        for (int c = 0; c < 8; ++c) {
            accA[c] = (float4v){0.f, 0.f, 0.f, 0.f};
            accB[c] = (float4v){0.f, 0.f, 0.f, 0.f};
        }
        #pragma unroll
        for (int s = 0; s < 4; ++s) {
            #pragma unroll
            for (int c = 0; c < 8; ++c) {
                short8 bfv = *(const short8*)&WF1[((c * 4 + s) * 64 + lane) * 8];
                accA[c] = __builtin_amdgcn_mfma_f32_16x16x32_bf16(afcA[s], bfv, accA[c], 0, 0, 0);
                accB[c] = __builtin_amdgcn_mfma_f32_16x16x32_bf16(afcB[s], bfv, accB[c], 0, 0, 0);
            }
        }
        ln_elu2(accA, accB, PIf, lnm);

        // convert next pair to bf16 frags (loads have had layer1+LN to land)
        if (pn < npairs) {
            #pragma unroll
            for (int s = 0; s < 4; ++s) {
                afcA[s] = packfrag(xfA[2 * s], xfA[2 * s + 1]);
                afcB[s] = packfrag(xfB[2 * s], xfB[2 * s + 1]);
            }
        }

        // L2 repack in PERMUTED feature order (one b128 per r per strip)
        #pragma unroll
        for (int r = 0; r < 4; ++r) {
            uint4 ua, ub;
            ua.x = pkbf(accA[0][r], accA[1][r]);
            ua.y = pkbf(accA[2][r], accA[3][r]);
            ua.z = pkbf(accA[4][r], accA[5][r]);
            ua.w = pkbf(accA[6][r], accA[7][r]);
            *(uint4*)&myFA[slotAddr(lnm, qu * 4 + r)] = ua;
            ub.x = pkbf(accB[0][r], accB[1][r]);
            ub.y = pkbf(accB[2][r], accB[3][r]);
            ub.z = pkbf(accB[4][r], accB[5][r]);
            ub.w = pkbf(accB[6][r], accB[7][r]);
            *(uint4*)&myFB[slotAddr(lnm, qu * 4 + r)] = ub;
        }

        // layer 2 MFMA (WF2 staged with matching k-permutation)
        #pragma unroll
        for (int c = 0; c < 8; ++c) {
            accA[c] = (float4v){0.f, 0.f, 0.f, 0.f};
            accB[c] = (float4v){0.f, 0.f, 0.f, 0.f};
        }
        #pragma unroll
        for (int s = 0; s < 4; ++s) {
            short8 afA = *(const short8*)&myFA[slotAddr(s * 4 + qu, lnm)];
            short8 afB = *(const short8*)&myFB[slotAddr(s * 4 + qu, lnm)];
            #pragma unroll
            for (int c = 0; c < 8; ++c) {
                short8 bfv = *(const short8*)&WF2[((c * 4 + s) * 64 + lane) * 8];
                accA[c] = __builtin_amdgcn_mfma_f32_16x16x32_bf16(afA, bfv, accA[c], 0, 0, 0);
                accB[c] = __builtin_amdgcn_mfma_f32_16x16x32_bf16(afB, bfv, accB[c], 0, 0, 0);
            }
        }
        ln_elu2(accA, accB, PIf + 512, lnm);

        // store h2 from registers, permuted feature layout; strips 2p,2p+1
        // are 32 contiguous rows -> stores coalesce across the pair.
        const size_t rowA = (size_t)(2 * pair) * 16;
        #pragma unroll
        for (int r = 0; r < 4; ++r) {
            uint4 ua, ub;
            ua.x = pkbf(accA[0][r], accA[1][r]);
            ua.y = pkbf(accA[2][r], accA[3][r]);
            ua.z = pkbf(accA[4][r], accA[5][r]);
            ua.w = pkbf(accA[6][r], accA[7][r]);
            *(uint4*)(h2out + (rowA + qu * 4 + r) * NF + lnm * 8) = ua;
            ub.x = pkbf(accB[0][r], accB[1][r]);
            ub.y = pkbf(accB[2][r], accB[3][r]);
            ub.z = pkbf(accB[4][r], accB[5][r]);
            ub.w = pkbf(accB[6][r], accB[7][r]);
            *(uint4*)(h2out + (rowA + 16 + qu * 4 + r) * NF + lnm * 8) = ub;
        }
    }
}

// ---------------- edge kernel ----------------
// h2 is in permuted feature layout; Wr1 staged with the same k-permutation.
// 512-thread blocks (8 waves), verified r10 config. LDS carve (shorts):
//   WFr [0,16384) | MYF [16384,16384+8*2048) | PI at 32768 shorts
#define E_MYF   16384
#define E_PI    32768
#define E_TOT   (32768 + 1024)          // shorts -> 67584 B

__global__ __launch_bounds__(512, 2)
void edge_kernel(const unsigned short* __restrict__ h2,
                 const int* __restrict__ pidx,
                 const float* __restrict__ Wr1, const float* __restrict__ br1,
                 const float* __restrict__ gr1, const float* __restrict__ ber1,
                 const float* __restrict__ Wr2, const float* __restrict__ br2,
                 float* __restrict__ rout)
{
    __shared__ __align__(16) unsigned short SH[E_TOT];

    const int tid  = threadIdx.x;
    const int lane = tid & 63;
    const int wave = tid >> 6;        // 0..7
    const int lnm  = lane & 15;
    const int qu   = lane >> 4;

    stage_wfrags<true, 512>(Wr1, &SH[0], tid);
    float* PIf = (float*)&SH[E_PI];
    if (tid < NF) {
        PIf[tid * 4 + 0] = br1[tid]; PIf[tid * 4 + 1] = gr1[tid];
        PIf[tid * 4 + 2] = ber1[tid];
    }

    float w2c[8];
    #pragma unroll
    for (int c = 0; c < 8; ++c) w2c[c] = Wr2[c * 16 + lnm];
    const float br2v = br2[0];

    unsigned short* myF = &SH[E_MYF + wave * 2048];
    const unsigned short* WFr = &SH[0];

    const int nstrips = NEDGE / 16;          // 16380
    const int sstep   = gridDim.x * 8;       // 2048
    const int s0      = blockIdx.x * 8 + wave;

    short8 cv[4], pv[4];
    int prn[4];
    if (s0 < nstrips) {
        int pr[4];
        #pragma unroll
        for (int t = 0; t < 4; ++t) pr[t] = pidx[s0 * 16 + t * 4 + qu];
        #pragma unroll
        for (int t = 0; t < 4; ++t) {
            int e = s0 * 16 + t * 4 + qu;
            int crow = e + (int)((unsigned)e / 4095u);
            cv[t] = *(const short8*)(h2 + (size_t)crow * NF + lnm * 8);
            pv[t] = *(const short8*)(h2 + (size_t)pr[t] * NF + lnm * 8);
        }
        int s1 = s0 + sstep;
        if (s1 < nstrips) {
            #pragma unroll
            for (int t = 0; t < 4; ++t) prn[t] = pidx[s1 * 16 + t * 4 + qu];
        }
    }
    __syncthreads();

    for (int strip = s0; strip < nstrips; strip += sstep) {
        // max in fp32, pack pairs, one b128 slot write per t
        #pragma unroll
        for (int t = 0; t < 4; ++t) {
            float m0 = fmaxf(bf2f((unsigned short)cv[t][0]), bf2f((unsigned short)pv[t][0]));
            float m1 = fmaxf(bf2f((unsigned short)cv[t][1]), bf2f((unsigned short)pv[t][1]));
            float m2 = fmaxf(bf2f((unsigned short)cv[t][2]), bf2f((unsigned short)pv[t][2]));
            float m3 = fmaxf(bf2f((unsigned short)cv[t][3]), bf2f((unsigned short)pv[t][3]));
            float m4 = fmaxf(bf2f((unsigned short)cv[t][4]), bf2f((unsigned short)pv[t][4]));
            float m5 = fmaxf(bf2f((unsigned short)cv[t][5]), bf2f((unsigned short)pv[t][5]));
            float m6 = fmaxf(bf2f((unsigned short)cv[t][6]), bf2f((unsigned short)pv[t][6]));
            float m7 = fmaxf(bf2f((unsigned short)cv[t][7]), bf2f((unsigned short)pv[t][7]));
            uint4 u;
            u.x = pkbf(m0, m1); u.y = pkbf(m2, m3);
            u.z = pkbf(m4, m5); u.w = pkbf(m6, m7);
            *(uint4*)&myF[slotAddr(lnm, t * 4 + qu)] = u;
        }

        // prefetch next strip's rows (pidx already in prn), pidx two ahead
        int sn = strip + sstep;
        if (sn < nstrips) {
            #pragma unroll
            for (int t = 0; t < 4; ++t) {
                int e = sn * 16 + t * 4 + qu;
                int crow = e + (int)((unsigned)e / 4095u);
                cv[t] = *(const short8*)(h2 + (size_t)crow * NF + lnm * 8);
                pv[t] = *(const short8*)(h2 + (size_t)prn[t] * NF + lnm * 8);
            }
            int sn2 = sn + sstep;
            if (sn2 < nstrips) {
                #pragma unroll
                for (int t = 0; t < 4; ++t) prn[t] = pidx[sn2 * 16 + t * 4 + qu];
            }
        }

        // MFMA + LN/ELU + dot(Wr2)
        float4v acc[8];
        #pragma unroll
        for (int c = 0; c < 8; ++c) acc[c] = (float4v){0.f, 0.f, 0.f, 0.f};
        #pragma unroll
        for (int s = 0; s < 4; ++s) {
            short8 af = *(const short8*)&myF[slotAddr(s * 4 + qu, lnm)];
            #pragma unroll
            for (int c = 0; c < 8; ++c) {
                short8 bfv = *(const short8*)&WFr[((c * 4 + s) * 64 + lane) * 8];
                acc[c] = __builtin_amdgcn_mfma_f32_16x16x32_bf16(af, bfv, acc[c], 0, 0, 0);
            }
        }
        ln_elu(acc, PIf, lnm);

        #pragma unroll
        for (int r = 0; r < 4; ++r) {
            float t2 = 0.f;
            #pragma unroll
            for (int c = 0; c < 8; ++c) t2 += acc[c][r] * w2c[c];
            t2 = red16(t2);
            if (lnm == 0) rout[strip * 16 + qu * 4 + r] = t2 + br2v;
        }
    }
}

__global__ __launch_bounds__(1024)
void lse_kernel(const float* __restrict__ r, float* __restrict__ out)
{
    __shared__ float red[1024];
    const int b = blockIdx.x;
    const float* rb = r + (size_t)b * 4095;

    float mx = -1e30f;
    for (int i = threadIdx.x; i < 4095; i += 1024) mx = fmaxf(mx, rb[i]);
    red[threadIdx.x] = mx;
    __syncthreads();
    for (int s = 512; s > 0; s >>= 1) {
        if (threadIdx.x < s) red[threadIdx.x] = fmaxf(red[threadIdx.x], red[threadIdx.x + s]);
        __syncthreads();
    }
    mx = red[0];
    __syncthreads();

    float sum = 0.f;
    for (int i = threadIdx.x; i < 4095; i += 1024) sum += __expf(rb[i] - mx);
    red[threadIdx.x] = sum;
    __syncthreads();
    for (int s = 512; s > 0; s >>= 1) {
        if (threadIdx.x < s) red[threadIdx.x] += red[threadIdx.x + s];
        __syncthreads();
    }
    float lse = mx + __logf(red[0]);

    for (int i = threadIdx.x; i < 4095; i += 1024)
        out[(size_t)b * 4095 + i] = rb[i] - lse;
}

extern "C" void kernel_launch(void* const* d_in, const int* in_sizes, int n_in,
                              void* d_out, int out_size, void* d_ws, size_t ws_size,
                              hipStream_t stream)
{
    const float* x    = (const float*)d_in[0];
    const int*   pidx = (const int*)d_in[1];
    const float* W1   = (const float*)d_in[2];
    const float* b1   = (const float*)d_in[3];
    const float* g1   = (const float*)d_in[4];
    const float* be1  = (const float*)d_in[5];
    const float* W2   = (const float*)d_in[6];
    const float* b2   = (const float*)d_in[7];
    const float* g2   = (const float*)d_in[8];
    const float* be2  = (const float*)d_in[9];
    const float* Wr1  = (const float*)d_in[10];
    const float* br1  = (const float*)d_in[11];
    const float* gr1  = (const float*)d_in[12];
    const float* ber1 = (const float*)d_in[13];
    const float* Wr2  = (const float*)d_in[14];
    const float* br2  = (const float*)d_in[15];
    float* out = (float*)d_out;

    // workspace: h2 (bf16, 64 MiB, permuted feature layout) | rbuf (fp32)
    unsigned short* h2 = (unsigned short*)d_ws;
    float* rbuf = (float*)(h2 + (size_t)MROWS * NF);

    fused12_kernel<<<256, 512, 0, stream>>>(x, W1, b1, g1, be1,
                                            W2, b2, g2, be2, h2);
    edge_kernel<<<256, 512, 0, stream>>>(h2, pidx, Wr1, br1, gr1, ber1,
                                         Wr2, br2, rbuf);
    lse_kernel<<<BATCH, 1024, 0, stream>>>(rbuf, out);
}

// Round 8
// 103.794 us; speedup vs baseline: 1.1730x; 1.1730x over previous
//
#include <hip/hip_runtime.h>
#include <hip/hip_bf16.h>

#define NF     128
#define BATCH  64
#define NNODES 4096
#define MROWS  (BATCH * NNODES)       // 262144
#define NEDGE  (BATCH * (NNODES - 1)) // 262080
#define LN_EPS 1e-5f

typedef short  short8  __attribute__((ext_vector_type(8)));
typedef float  float4v __attribute__((ext_vector_type(4)));

__device__ __forceinline__ unsigned short f2bf(float f) {
    union { float f; unsigned u; } v; v.f = f;
    unsigned r = v.u;
    r = r + 0x7FFF + ((r >> 16) & 1);   // RNE
    return (unsigned short)(r >> 16);
}
__device__ __forceinline__ float bf2f(unsigned short b) {
    union { unsigned u; float f; } v; v.u = ((unsigned)b) << 16;
    return v.f;
}
// packed f32x2 -> bf16x2 (v_cvt_pk_bf16_f32), low short = lo. RNE == f2bf.
__device__ __forceinline__ unsigned pkbf(float lo, float hi) {
    __hip_bfloat162 h = __float22bfloat162_rn(float2{lo, hi});
    union { __hip_bfloat162 h; unsigned u; } v; v.h = h;
    return v.u;
}
// 8 fp32 -> one A-fragment octet (short8 of bf16); layout verified r7/r12.
__device__ __forceinline__ short8 packfrag(float4v a, float4v b) {
    union { short8 s; unsigned u[4]; } v;
    v.u[0] = pkbf(a[0], a[1]); v.u[1] = pkbf(a[2], a[3]);
    v.u[2] = pkbf(b[0], b[1]); v.u[3] = pkbf(b[2], b[3]);
    return v.s;
}

// DPP 16-lane sum (VALU pipe, no LDS). Exact for aligned 16-lane groups.
template <int CTRL>
__device__ __forceinline__ float dppadd(float v) {
    union { float f; int i; } a, b; a.f = v;
    b.i = __builtin_amdgcn_mov_dpp(a.i, CTRL, 0xF, 0xF, true);
    return v + b.f;
}
__device__ __forceinline__ float red16(float v) {
    v = dppadd<0xB1>(v);    // quad_perm ^1
    v = dppadd<0x4E>(v);    // quad_perm ^2
    v = dppadd<0x141>(v);   // row_half_mirror (== ^4 after quad-uniform)
    v = dppadd<0x140>(v);   // row_mirror      (== ^8 after half-uniform)
    return v;
}

// A-fragment slot address (shorts): slot(q,m) holds A[m][k-octet q] (16 B).
// XOR swizzle spreads bank groups (validated r4-r6).
__device__ __forceinline__ int slotAddr(int q, int m) {
    return ((q * 16 + m) ^ (q & 7)) * 8;
}

// Stage W (128x128 fp32, k-major) into WF in bf16 MFMA B-fragment order.
// PERM: k-row k is placed at fragment position p=(k&15)*8+(k>>4), matching the
// permuted feature layout n(p)=(p&7)*16+(p>>3) used for h1-slots and h2.
// NT = block size in threads (generic strided loop).
template <bool PERM, int NT>
__device__ __forceinline__ void stage_wfrags(const float* __restrict__ W,
                                             unsigned short* __restrict__ WF,
                                             int tid) {
    for (int g = tid; g < 4096; g += NT) {
        int k  = g >> 5;                  // true input-feature row 0..127
        int n0 = (g & 31) * 4;
        float4v wv = *(const float4v*)(W + k * NF + n0);
        int p = PERM ? ((k & 15) * 8 + (k >> 4)) : k;
        int s = p >> 5, q = (p & 31) >> 3, j = p & 7;
        #pragma unroll
        for (int e = 0; e < 4; ++e) {
            int n = n0 + e;
            WF[((((n >> 4) * 4 + s) * 64) + q * 16 + (n & 15)) * 8 + j] = f2bf(wv[e]);
        }
    }
}

// bias + LayerNorm(128) + ELU on C-layout accumulators (r6-verified form;
// r8's 3-pass variant failed correctness — do not touch without disasm).
__device__ __forceinline__ void ln_elu(float4v acc[8], const float* __restrict__ PI,
                                       int lnm) {
    float bias[8], gn[8], bt[8];
    #pragma unroll
    for (int c = 0; c < 8; ++c) {
        float4v prm = *(const float4v*)&PI[(c * 16 + lnm) * 4];
        bias[c] = prm[0]; gn[c] = prm[1]; bt[c] = prm[2];
    }
    #pragma unroll
    for (int r = 0; r < 4; ++r) {
        float s1 = 0.f, s2 = 0.f;
        #pragma unroll
        for (int c = 0; c < 8; ++c) {
            float t = acc[c][r] + bias[c];
            acc[c][r] = t;
            s1 += t; s2 += t * t;
        }
        s1 = red16(s1);
        s2 = red16(s2);
        float mu  = s1 * (1.0f / 128.0f);
        float var = s2 * (1.0f / 128.0f) - mu * mu;
        float rs  = rsqrtf(var + LN_EPS);
        #pragma unroll
        for (int c = 0; c < 8; ++c) {
            float y = (acc[c][r] - mu) * rs * gn[c] + bt[c];
            acc[c][r] = (y > 0.f) ? y : (__expf(y) - 1.0f);
        }
    }
}

// ---------------- fused layer1+layer2 ----------------
// r14: 768 threads (12 waves, 3/SIMD) + r12 dataflow + SPLIT-HALF prefetch.
// LDS carve (shorts): WF1 [0,16384) | WF2 [16384,32768) |
//   MYF [32768, 32768+12*2048) | PI (floats) at 57344: 2 sets x 512 floats
#define F_MYF   32768
#define F_PI    57344
#define F_TOT   (57344 + 2048)          // shorts -> 118784 B (116 KB)

// History: unified VGPR budget splits ~50/50 arch/acc (r6: 64a@128u;
// r13: 128a@256u). r12 @ (512,2): 88 arch, no spill, fused12=78us, but
// Occ 18% / 60% idle = latency-bound at 2 waves/SIMD. r11 @ (768,3) with
// UNSPLIT prefetch (demand ~88a > 85a budget) squeezed to 76 and regressed.
// r14 cuts arch demand: xf[8] (32 regs, the biggest consumer) -> xf[4]
// (16) with register reuse: half1 issued at loop top (packed after LN1),
// half2 issued after LN1 into the SAME regs (packed at body end). Peak
// arch ~68 < 85 -> 3 waves/SIMD without squeeze or spill.
__global__ __launch_bounds__(768, 3)
void fused12_kernel(const float* __restrict__ x,
                    const float* __restrict__ W1, const float* __restrict__ b1,
                    const float* __restrict__ g1, const float* __restrict__ be1,
                    const float* __restrict__ W2, const float* __restrict__ b2,
                    const float* __restrict__ g2, const float* __restrict__ be2,
                    unsigned short* __restrict__ h2out)
{
    __shared__ __align__(16) unsigned short SH[F_TOT];

    const int tid  = threadIdx.x;
    const int lane = tid & 63;
    const int wave = tid >> 6;        // 0..11
    const int lnm  = lane & 15;
    const int qu   = lane >> 4;

    stage_wfrags<false, 768>(W1, &SH[0], tid);
    stage_wfrags<true , 768>(W2, &SH[16384], tid);
    float* PIf = (float*)&SH[F_PI];
    if (tid < NF) {
        PIf[tid * 4 + 0] = b1[tid]; PIf[tid * 4 + 1] = g1[tid]; PIf[tid * 4 + 2] = be1[tid];
        PIf[512 + tid * 4 + 0] = b2[tid]; PIf[512 + tid * 4 + 1] = g2[tid];
        PIf[512 + tid * 4 + 2] = be2[tid];
    }

    unsigned short* myF = &SH[F_MYF + wave * 2048];
    const unsigned short* WF1 = &SH[0];
    const unsigned short* WF2 = &SH[16384];

    const int nstrips = MROWS / 16;          // 16384
    const int sstep   = gridDim.x * 12;      // 3072
    int strip = blockIdx.x * 12 + wave;

    // fragment-order x loads (r12-verified): lane (qu,lnm) reads row lnm,
    // float octet s*4+qu -> xr + s*32 (+4). s=0,1 = half1; s=2,3 = half2.
    const int laneOff = lnm * NF + qu * 8;

    float4v xf[4];
    short8  afc[4];
    if (strip < nstrips) {
        const float* xr = x + (size_t)strip * (16 * NF) + laneOff;
        xf[0] = *(const float4v*)(xr + 0);
        xf[1] = *(const float4v*)(xr + 4);
        xf[2] = *(const float4v*)(xr + 32);
        xf[3] = *(const float4v*)(xr + 36);
        afc[0] = packfrag(xf[0], xf[1]);
        afc[1] = packfrag(xf[2], xf[3]);
        xf[0] = *(const float4v*)(xr + 64);
        xf[1] = *(const float4v*)(xr + 68);
        xf[2] = *(const float4v*)(xr + 96);
        xf[3] = *(const float4v*)(xr + 100);
        afc[2] = packfrag(xf[0], xf[1]);
        afc[3] = packfrag(xf[2], xf[3]);
    }
    __syncthreads();

    for (; strip < nstrips; strip += sstep) {
        int sn = strip + sstep;
        const float* xrn = x + (size_t)sn * (16 * NF) + laneOff;

        // (A) issue HALF1 of next strip (hidden under layer1 + LN1)
        if (sn < nstrips) {
            xf[0] = *(const float4v*)(xrn + 0);
            xf[1] = *(const float4v*)(xrn + 4);
            xf[2] = *(const float4v*)(xrn + 32);
            xf[3] = *(const float4v*)(xrn + 36);
        }

        // (B) layer 1 MFMA: A from registers, B from LDS
        float4v acc[8];
        #pragma unroll
        for (int c = 0; c < 8; ++c) acc[c] = (float4v){0.f, 0.f, 0.f, 0.f};
        #pragma unroll
        for (int s = 0; s < 4; ++s) {
            #pragma unroll
            for (int c = 0; c < 8; ++c) {
                short8 bfv = *(const short8*)&WF1[((c * 4 + s) * 64 + lane) * 8];
                acc[c] = __builtin_amdgcn_mfma_f32_16x16x32_bf16(afc[s], bfv, acc[c], 0, 0, 0);
            }
        }
        // (C)
        ln_elu(acc, PIf, lnm);

        // (D) pack half1 (afc dead after B -> reuse slots 0,1);
        //     issue HALF2 into the SAME xf regs (hidden under E)
        if (sn < nstrips) {
            afc[0] = packfrag(xf[0], xf[1]);
            afc[1] = packfrag(xf[2], xf[3]);
            xf[0] = *(const float4v*)(xrn + 64);
            xf[1] = *(const float4v*)(xrn + 68);
            xf[2] = *(const float4v*)(xrn + 96);
            xf[3] = *(const float4v*)(xrn + 100);
        }

        // (E) L2 repack in PERMUTED feature order: lane's 8 c-values for row
        // m=qu*4+r are contiguous at positions lnm*8..+7 -> one b128 per r.
        #pragma unroll
        for (int r = 0; r < 4; ++r) {
            uint4 u;
            u.x = pkbf(acc[0][r], acc[1][r]);
            u.y = pkbf(acc[2][r], acc[3][r]);
            u.z = pkbf(acc[4][r], acc[5][r]);
            u.w = pkbf(acc[6][r], acc[7][r]);
            *(uint4*)&myF[slotAddr(lnm, qu * 4 + r)] = u;
        }

        // layer 2 MFMA (WF2 staged with matching k-permutation)
        #pragma unroll
        for (int c = 0; c < 8; ++c) acc[c] = (float4v){0.f, 0.f, 0.f, 0.f};
        #pragma unroll
        for (int s = 0; s < 4; ++s) {
            short8 af = *(const short8*)&myF[slotAddr(s * 4 + qu, lnm)];
            #pragma unroll
            for (int c = 0; c < 8; ++c) {
                short8 bfv = *(const short8*)&WF2[((c * 4 + s) * 64 + lane) * 8];
                acc[c] = __builtin_amdgcn_mfma_f32_16x16x32_bf16(af, bfv, acc[c], 0, 0, 0);
            }
        }
        ln_elu(acc, PIf + 512, lnm);

        // store h2 DIRECTLY from registers in permuted feature layout:
        // position p=lnm*8+c of row holds feature 16c+lnm. 16 B/lane, rows
        // qu*4+r: 4 fully-covered 256-B segments per instruction.
        const size_t rowBase = (size_t)strip * 16;
        #pragma unroll
        for (int r = 0; r < 4; ++r) {
            uint4 u;
            u.x = pkbf(acc[0][r], acc[1][r]);
            u.y = pkbf(acc[2][r], acc[3][r]);
            u.z = pkbf(acc[4][r], acc[5][r]);
            u.w = pkbf(acc[6][r], acc[7][r]);
            *(uint4*)(h2out + (rowBase + qu * 4 + r) * NF + lnm * 8) = u;
        }

        // (F) pack half2 at body end (loads have had E to land); afc now
        // complete for the next iteration's layer1.
        if (sn < nstrips) {
            afc[2] = packfrag(xf[0], xf[1]);
            afc[3] = packfrag(xf[2], xf[3]);
        }
    }
}

// ---------------- edge kernel ----------------
// h2 is in permuted feature layout; Wr1 staged with the same k-permutation.
// 512-thread blocks (8 waves), verified r10 config. LDS carve (shorts):
//   WFr [0,16384) | MYF [16384,16384+8*2048) | PI at 32768 shorts
#define E_MYF   16384
#define E_PI    32768
#define E_TOT   (32768 + 1024)          // shorts -> 67584 B

__global__ __launch_bounds__(512, 2)
void edge_kernel(const unsigned short* __restrict__ h2,
                 const int* __restrict__ pidx,
                 const float* __restrict__ Wr1, const float* __restrict__ br1,
                 const float* __restrict__ gr1, const float* __restrict__ ber1,
                 const float* __restrict__ Wr2, const float* __restrict__ br2,
                 float* __restrict__ rout)
{
    __shared__ __align__(16) unsigned short SH[E_TOT];

    const int tid  = threadIdx.x;
    const int lane = tid & 63;
    const int wave = tid >> 6;        // 0..7
    const int lnm  = lane & 15;
    const int qu   = lane >> 4;

    stage_wfrags<true, 512>(Wr1, &SH[0], tid);
    float* PIf = (float*)&SH[E_PI];
    if (tid < NF) {
        PIf[tid * 4 + 0] = br1[tid]; PIf[tid * 4 + 1] = gr1[tid];
        PIf[tid * 4 + 2] = ber1[tid];
    }

    float w2c[8];
    #pragma unroll
    for (int c = 0; c < 8; ++c) w2c[c] = Wr2[c * 16 + lnm];
    const float br2v = br2[0];

    unsigned short* myF = &SH[E_MYF + wave * 2048];
    const unsigned short* WFr = &SH[0];

    const int nstrips = NEDGE / 16;          // 16380
    const int sstep   = gridDim.x * 8;       // 2048
    const int s0      = blockIdx.x * 8 + wave;

    short8 cv[4], pv[4];
    int prn[4];
    if (s0 < nstrips) {
        int pr[4];
        #pragma unroll
        for (int t = 0; t < 4; ++t) pr[t] = pidx[s0 * 16 + t * 4 + qu];
        #pragma unroll
        for (int t = 0; t < 4; ++t) {
            int e = s0 * 16 + t * 4 + qu;
            int crow = e + (int)((unsigned)e / 4095u);
            cv[t] = *(const short8*)(h2 + (size_t)crow * NF + lnm * 8);
            pv[t] = *(const short8*)(h2 + (size_t)pr[t] * NF + lnm * 8);
        }
        int s1 = s0 + sstep;
        if (s1 < nstrips) {
            #pragma unroll
            for (int t = 0; t < 4; ++t) prn[t] = pidx[s1 * 16 + t * 4 + qu];
        }
    }
    __syncthreads();

    for (int strip = s0; strip < nstrips; strip += sstep) {
        // max in fp32, pack pairs, one b128 slot write per t
        #pragma unroll
        for (int t = 0; t < 4; ++t) {
            float m0 = fmaxf(bf2f((unsigned short)cv[t][0]), bf2f((unsigned short)pv[t][0]));
            float m1 = fmaxf(bf2f((unsigned short)cv[t][1]), bf2f((unsigned short)pv[t][1]));
            float m2 = fmaxf(bf2f((unsigned short)cv[t][2]), bf2f((unsigned short)pv[t][2]));
            float m3 = fmaxf(bf2f((unsigned short)cv[t][3]), bf2f((unsigned short)pv[t][3]));
            float m4 = fmaxf(bf2f((unsigned short)cv[t][4]), bf2f((unsigned short)pv[t][4]));
            float m5 = fmaxf(bf2f((unsigned short)cv[t][5]), bf2f((unsigned short)pv[t][5]));
            float m6 = fmaxf(bf2f((unsigned short)cv[t][6]), bf2f((unsigned short)pv[t][6]));
            float m7 = fmaxf(bf2f((unsigned short)cv[t][7]), bf2f((unsigned short)pv[t][7]));
            uint4 u;
            u.x = pkbf(m0, m1); u.y = pkbf(m2, m3);
            u.z = pkbf(m4, m5); u.w = pkbf(m6, m7);
            *(uint4*)&myF[slotAddr(lnm, t * 4 + qu)] = u;
        }

        // prefetch next strip's rows (pidx already in prn), pidx two ahead
        int sn = strip + sstep;
        if (sn < nstrips) {
            #pragma unroll
            for (int t = 0; t < 4; ++t) {
                int e = sn * 16 + t * 4 + qu;
                int crow = e + (int)((unsigned)e / 4095u);
                cv[t] = *(const short8*)(h2 + (size_t)crow * NF + lnm * 8);
                pv[t] = *(const short8*)(h2 + (size_t)prn[t] * NF + lnm * 8);
            }
            int sn2 = sn + sstep;
            if (sn2 < nstrips) {
                #pragma unroll
                for (int t = 0; t < 4; ++t) prn[t] = pidx[sn2 * 16 + t * 4 + qu];
            }
        }

        // MFMA + LN/ELU + dot(Wr2)
        float4v acc[8];
        #pragma unroll
        for (int c = 0; c < 8; ++c) acc[c] = (float4v){0.f, 0.f, 0.f, 0.f};
        #pragma unroll
        for (int s = 0; s < 4; ++s) {
            short8 af = *(const short8*)&myF[slotAddr(s * 4 + qu, lnm)];
            #pragma unroll
            for (int c = 0; c < 8; ++c) {
                short8 bfv = *(const short8*)&WFr[((c * 4 + s) * 64 + lane) * 8];
                acc[c] = __builtin_amdgcn_mfma_f32_16x16x32_bf16(af, bfv, acc[c], 0, 0, 0);
            }
        }
        ln_elu(acc, PIf, lnm);

        #pragma unroll
        for (int r = 0; r < 4; ++r) {
            float t2 = 0.f;
            #pragma unroll
            for (int c = 0; c < 8; ++c) t2 += acc[c][r] * w2c[c];
            t2 = red16(t2);
            if (lnm == 0) rout[strip * 16 + qu * 4 + r] = t2 + br2v;
        }
    }
}

__global__ __launch_bounds__(1024)
void lse_kernel(const float* __restrict__ r, float* __restrict__ out)
{
    __shared__ float red[1024];
    const int b = blockIdx.x;
    const float* rb = r + (size_t)b * 4095;

    float mx = -1e30f;
    for (int i = threadIdx.x; i < 4095; i += 1024) mx = fmaxf(mx, rb[i]);
    red[threadIdx.x] = mx;
    __syncthreads();
    for (int s = 512; s > 0; s >>= 1) {
        if (threadIdx.x < s) red[threadIdx.x] = fmaxf(red[threadIdx.x], red[threadIdx.x + s]);
        __syncthreads();
    }
    mx = red[0];
    __syncthreads();

    float sum = 0.f;
    for (int i = threadIdx.x; i < 4095; i += 1024) sum += __expf(rb[i] - mx);
    red[threadIdx.x] = sum;
    __syncthreads();
    for (int s = 512; s > 0; s >>= 1) {
        if (threadIdx.x < s) red[threadIdx.x] += red[threadIdx.x + s];
        __syncthreads();
    }
    float lse = mx + __logf(red[0]);

    for (int i = threadIdx.x; i < 4095; i += 1024)
        out[(size_t)b * 4095 + i] = rb[i] - lse;
}

extern "C" void kernel_launch(void* const* d_in, const int* in_sizes, int n_in,
                              void* d_out, int out_size, void* d_ws, size_t ws_size,
                              hipStream_t stream)
{
    const float* x    = (const float*)d_in[0];
    const int*   pidx = (const int*)d_in[1];
    const float* W1   = (const float*)d_in[2];
    const float* b1   = (const float*)d_in[3];
    const float* g1   = (const float*)d_in[4];
    const float* be1  = (const float*)d_in[5];
    const float* W2   = (const float*)d_in[6];
    const float* b2   = (const float*)d_in[7];
    const float* g2   = (const float*)d_in[8];
    const float* be2  = (const float*)d_in[9];
    const float* Wr1  = (const float*)d_in[10];
    const float* br1  = (const float*)d_in[11];
    const float* gr1  = (const float*)d_in[12];
    const float* ber1 = (const float*)d_in[13];
    const float* Wr2  = (const float*)d_in[14];
    const float* br2  = (const float*)d_in[15];
    float* out = (float*)d_out;

    // workspace: h2 (bf16, 64 MiB, permuted feature layout) | rbuf (fp32)
    unsigned short* h2 = (unsigned short*)d_ws;
    float* rbuf = (float*)(h2 + (size_t)MROWS * NF);

    fused12_kernel<<<256, 768, 0, stream>>>(x, W1, b1, g1, be1,
                                            W2, b2, g2, be2, h2);
    edge_kernel<<<256, 512, 0, stream>>>(h2, pidx, Wr1, br1, gr1, ber1,
                                         Wr2, br2, rbuf);
    lse_kernel<<<BATCH, 1024, 0, stream>>>(rbuf, out);
}

// Round 10
// 102.690 us; speedup vs baseline: 1.1856x; 1.0108x over previous
//
#include <hip/hip_runtime.h>
#include <hip/hip_bf16.h>

#define NF     128
#define BATCH  64
#define NNODES 4096
#define MROWS  (BATCH * NNODES)       // 262144
#define NEDGE  (BATCH * (NNODES - 1)) // 262080
#define LN_EPS 1e-5f

typedef short  short8  __attribute__((ext_vector_type(8)));
typedef float  float4v __attribute__((ext_vector_type(4)));

__device__ __forceinline__ unsigned short f2bf(float f) {
    union { float f; unsigned u; } v; v.f = f;
    unsigned r = v.u;
    r = r + 0x7FFF + ((r >> 16) & 1);   // RNE
    return (unsigned short)(r >> 16);
}
__device__ __forceinline__ float bf2f(unsigned short b) {
    union { unsigned u; float f; } v; v.u = ((unsigned)b) << 16;
    return v.f;
}
// packed f32x2 -> bf16x2 (v_cvt_pk_bf16_f32), low short = lo. RNE == f2bf.
__device__ __forceinline__ unsigned pkbf(float lo, float hi) {
    __hip_bfloat162 h = __float22bfloat162_rn(float2{lo, hi});
    union { __hip_bfloat162 h; unsigned u; } v; v.h = h;
    return v.u;
}
// 8 fp32 -> one A-fragment octet (short8 of bf16); layout verified r7/r12.
__device__ __forceinline__ short8 packfrag(float4v a, float4v b) {
    union { short8 s; unsigned u[4]; } v;
    v.u[0] = pkbf(a[0], a[1]); v.u[1] = pkbf(a[2], a[3]);
    v.u[2] = pkbf(b[0], b[1]); v.u[3] = pkbf(b[2], b[3]);
    return v.s;
}

// DPP 16-lane sum (VALU pipe, no LDS). Exact for aligned 16-lane groups.
template <int CTRL>
__device__ __forceinline__ float dppadd(float v) {
    union { float f; int i; } a, b; a.f = v;
    b.i = __builtin_amdgcn_mov_dpp(a.i, CTRL, 0xF, 0xF, true);
    return v + b.f;
}
__device__ __forceinline__ float red16(float v) {
    v = dppadd<0xB1>(v);    // quad_perm ^1
    v = dppadd<0x4E>(v);    // quad_perm ^2
    v = dppadd<0x141>(v);   // row_half_mirror (== ^4 after quad-uniform)
    v = dppadd<0x140>(v);   // row_mirror      (== ^8 after half-uniform)
    return v;
}

// A-fragment slot address (shorts): slot(q,m) holds A[m][k-octet q] (16 B).
// XOR swizzle spreads bank groups (validated r4-r6).
__device__ __forceinline__ int slotAddr(int q, int m) {
    return ((q * 16 + m) ^ (q & 7)) * 8;
}

// Stage W (128x128 fp32, k-major) into WF in bf16 MFMA B-fragment order.
// PERM: k-row k is placed at fragment position p=(k&15)*8+(k>>4), matching the
// permuted feature layout n(p)=(p&7)*16+(p>>3) used for h1-slots and h2.
// NT = block size in threads (generic strided loop).
template <bool PERM, int NT>
__device__ __forceinline__ void stage_wfrags(const float* __restrict__ W,
                                             unsigned short* __restrict__ WF,
                                             int tid) {
    for (int g = tid; g < 4096; g += NT) {
        int k  = g >> 5;                  // true input-feature row 0..127
        int n0 = (g & 31) * 4;
        float4v wv = *(const float4v*)(W + k * NF + n0);
        int p = PERM ? ((k & 15) * 8 + (k >> 4)) : k;
        int s = p >> 5, q = (p & 31) >> 3, j = p & 7;
        #pragma unroll
        for (int e = 0; e < 4; ++e) {
            int n = n0 + e;
            WF[((((n >> 4) * 4 + s) * 64) + q * 16 + (n & 15)) * 8 + j] = f2bf(wv[e]);
        }
    }
}

// bias + LayerNorm(128) + ELU on C-layout accumulators.
// PI: interleaved params PI[n*4 + {0:bias,1:gain,2:beta}] (stride-4 floats).
// r6-VERIFIED form. r8 (3-pass) and r15 (packed-f32) rewrites BOTH failed
// correctness for unexplained reasons — DO NOT restructure this function.
__device__ __forceinline__ void ln_elu(float4v acc[8], const float* __restrict__ PI,
                                       int lnm) {
    float bias[8], gn[8], bt[8];
    #pragma unroll
    for (int c = 0; c < 8; ++c) {
        float4v prm = *(const float4v*)&PI[(c * 16 + lnm) * 4];
        bias[c] = prm[0]; gn[c] = prm[1]; bt[c] = prm[2];
    }
    #pragma unroll
    for (int r = 0; r < 4; ++r) {
        float s1 = 0.f, s2 = 0.f;
        #pragma unroll
        for (int c = 0; c < 8; ++c) {
            float t = acc[c][r] + bias[c];
            acc[c][r] = t;
            s1 += t; s2 += t * t;
        }
        s1 = red16(s1);
        s2 = red16(s2);
        float mu  = s1 * (1.0f / 128.0f);
        float var = s2 * (1.0f / 128.0f) - mu * mu;
        float rs  = rsqrtf(var + LN_EPS);
        #pragma unroll
        for (int c = 0; c < 8; ++c) {
            float y = (acc[c][r] - mu) * rs * gn[c] + bt[c];
            acc[c][r] = (y > 0.f) ? y : (__expf(y) - 1.0f);
        }
    }
}

// Dual-strip LN — r13-VERIFIED (passed absmax 0.125). Same per-element ops
// as ln_elu on each acc set; only the param loads are shared.
__device__ __forceinline__ void ln_elu2(float4v a[8], float4v b[8],
                                        const float* __restrict__ PI, int lnm) {
    float bias[8], gn[8], bt[8];
    #pragma unroll
    for (int c = 0; c < 8; ++c) {
        float4v prm = *(const float4v*)&PI[(c * 16 + lnm) * 4];
        bias[c] = prm[0]; gn[c] = prm[1]; bt[c] = prm[2];
    }
    #pragma unroll
    for (int r = 0; r < 4; ++r) {
        float s1a = 0.f, s2a = 0.f, s1b = 0.f, s2b = 0.f;
        #pragma unroll
        for (int c = 0; c < 8; ++c) {
            float ta = a[c][r] + bias[c];
            a[c][r] = ta; s1a += ta; s2a += ta * ta;
            float tb = b[c][r] + bias[c];
            b[c][r] = tb; s1b += tb; s2b += tb * tb;
        }
        s1a = red16(s1a); s2a = red16(s2a);
        s1b = red16(s1b); s2b = red16(s2b);
        float mua = s1a * (1.0f / 128.0f);
        float vara = s2a * (1.0f / 128.0f) - mua * mua;
        float rsa = rsqrtf(vara + LN_EPS);
        float mub = s1b * (1.0f / 128.0f);
        float varb = s2b * (1.0f / 128.0f) - mub * mub;
        float rsb = rsqrtf(varb + LN_EPS);
        #pragma unroll
        for (int c = 0; c < 8; ++c) {
            float ya = (a[c][r] - mua) * rsa * gn[c] + bt[c];
            a[c][r] = (ya > 0.f) ? ya : (__expf(ya) - 1.0f);
            float yb = (b[c][r] - mub) * rsb * gn[c] + bt[c];
            b[c][r] = (yb > 0.f) ? yb : (__expf(yb) - 1.0f);
        }
    }
}

// ---------------- fused layer1+layer2 ----------------
// r16: dual-strip ILP (r13 structure, correctness-verified) + quartered
// prefetch through ONE xf[4] buffer (r14 trick, spill-free-verified).
// 512 threads (8 waves, (512,2) config). LDS carve (shorts):
//   WF1 [0,16384) | WF2 [16384,32768) | MYF [32768, 32768+8*4096) |
//   PI (floats) at 65536: 2 sets x 512 floats
#define F_MYF   32768
#define F_PI    65536
#define F_TOT   (65536 + 2048)          // shorts -> 135168 B

// History: (512,2) = 256 unified VGPR/wave, split ~50/50 arch/acc.
// r13 dual-strip passed correctness but spilled (xfA+xfB = 64 arch fp32
// prefetch regs -> 130+ arch > 128). r16 replaces that with the r14
// quartered schedule: 4 load-quarters (4 float4 each) rotate through one
// xf[4] (16 regs), each packed to bf16 one major phase after issue.
// Arch peak ~110 < 128; acc = accA+accB = 64 < 128. Win mechanism: each
// WF B-fragment ds_read feeds 2 MFMAs; two independent LN chains overlap;
// LN params amortize; strips 2p/2p+1 contiguous for x-loads and h2 stores.
__global__ __launch_bounds__(512, 2)
void fused12_kernel(const float* __restrict__ x,
                    const float* __restrict__ W1, const float* __restrict__ b1,
                    const float* __restrict__ g1, const float* __restrict__ be1,
                    const float* __restrict__ W2, const float* __restrict__ b2,
                    const float* __restrict__ g2, const float* __restrict__ be2,
                    unsigned short* __restrict__ h2out)
{
    __shared__ __align__(16) unsigned short SH[F_TOT];

    const int tid  = threadIdx.x;
    const int lane = tid & 63;
    const int wave = tid >> 6;        // 0..7
    const int lnm  = lane & 15;
    const int qu   = lane >> 4;

    stage_wfrags<false, 512>(W1, &SH[0], tid);
    stage_wfrags<true , 512>(W2, &SH[16384], tid);
    float* PIf = (float*)&SH[F_PI];
    if (tid < NF) {
        PIf[tid * 4 + 0] = b1[tid]; PIf[tid * 4 + 1] = g1[tid]; PIf[tid * 4 + 2] = be1[tid];
        PIf[512 + tid * 4 + 0] = b2[tid]; PIf[512 + tid * 4 + 1] = g2[tid];
        PIf[512 + tid * 4 + 2] = be2[tid];
    }

    unsigned short* myFA = &SH[F_MYF + wave * 4096];
    unsigned short* myFB = myFA + 2048;
    const unsigned short* WF1 = &SH[0];
    const unsigned short* WF2 = &SH[16384];

    const int npairs = MROWS / 32;           // 8192 strip-pairs
    const int pstep  = gridDim.x * 8;        // 2048
    int pair = blockIdx.x * 8 + wave;

    // fragment-order x loads (r12-verified): lane (qu,lnm) reads row lnm,
    // float octet s*4+qu -> base + s*32 (+4).
    const int laneOff = lnm * NF + qu * 8;

    float4v xf[4];
    short8  afcA[4], afcB[4];
    if (pair < npairs) {
        const float* xrA = x + (size_t)(2 * pair) * (16 * NF) + laneOff;
        const float* xrB = xrA + 16 * NF;
        xf[0] = *(const float4v*)(xrA + 0);
        xf[1] = *(const float4v*)(xrA + 4);
        xf[2] = *(const float4v*)(xrA + 32);
        xf[3] = *(const float4v*)(xrA + 36);
        afcA[0] = packfrag(xf[0], xf[1]);
        afcA[1] = packfrag(xf[2], xf[3]);
        xf[0] = *(const float4v*)(xrA + 64);
        xf[1] = *(const float4v*)(xrA + 68);
        xf[2] = *(const float4v*)(xrA + 96);
        xf[3] = *(const float4v*)(xrA + 100);
        afcA[2] = packfrag(xf[0], xf[1]);
        afcA[3] = packfrag(xf[2], xf[3]);
        xf[0] = *(const float4v*)(xrB + 0);
        xf[1] = *(const float4v*)(xrB + 4);
        xf[2] = *(const float4v*)(xrB + 32);
        xf[3] = *(const float4v*)(xrB + 36);
        afcB[0] = packfrag(xf[0], xf[1]);
        afcB[1] = packfrag(xf[2], xf[3]);
        xf[0] = *(const float4v*)(xrB + 64);
        xf[1] = *(const float4v*)(xrB + 68);
        xf[2] = *(const float4v*)(xrB + 96);
        xf[3] = *(const float4v*)(xrB + 100);
        afcB[2] = packfrag(xf[0], xf[1]);
        afcB[3] = packfrag(xf[2], xf[3]);
    }
    __syncthreads();

    for (; pair < npairs; pair += pstep) {
        int pn = pair + pstep;
        const float* xrA = x + (size_t)(2 * pn) * (16 * NF) + laneOff;
        const float* xrB = xrA + 16 * NF;

        // (q1) issue next-A half1 (packs after LN1; ~2700 cy to land)
        if (pn < npairs) {
            xf[0] = *(const float4v*)(xrA + 0);
            xf[1] = *(const float4v*)(xrA + 4);
            xf[2] = *(const float4v*)(xrA + 32);
            xf[3] = *(const float4v*)(xrA + 36);
        }

        // layer 1 dual MFMA: each B-fragment read feeds both strips
        float4v accA[8], accB[8];
        #pragma unroll
        for (int c = 0; c < 8; ++c) {
            accA[c] = (float4v){0.f, 0.f, 0.f, 0.f};
            accB[c] = (float4v){0.f, 0.f, 0.f, 0.f};
        }
        #pragma unroll
        for (int s = 0; s < 4; ++s) {
            #pragma unroll
            for (int c = 0; c < 8; ++c) {
                short8 bfv = *(const short8*)&WF1[((c * 4 + s) * 64 + lane) * 8];
                accA[c] = __builtin_amdgcn_mfma_f32_16x16x32_bf16(afcA[s], bfv, accA[c], 0, 0, 0);
                accB[c] = __builtin_amdgcn_mfma_f32_16x16x32_bf16(afcB[s], bfv, accB[c], 0, 0, 0);
            }
        }
        ln_elu2(accA, accB, PIf, lnm);

        // pack q1 -> afcA[0,1] (old afcA consumed by L1); issue q2 (next-A
        // half2; packs after L2, ~1900 cy to land)
        if (pn < npairs) {
            afcA[0] = packfrag(xf[0], xf[1]);
            afcA[1] = packfrag(xf[2], xf[3]);
            xf[0] = *(const float4v*)(xrA + 64);
            xf[1] = *(const float4v*)(xrA + 68);
            xf[2] = *(const float4v*)(xrA + 96);
            xf[3] = *(const float4v*)(xrA + 100);
        }

        // L2 repack in PERMUTED feature order (one b128 per r per strip)
        #pragma unroll
        for (int r = 0; r < 4; ++r) {
            uint4 ua, ub;
            ua.x = pkbf(accA[0][r], accA[1][r]);
            ua.y = pkbf(accA[2][r], accA[3][r]);
            ua.z = pkbf(accA[4][r], accA[5][r]);
            ua.w = pkbf(accA[6][r], accA[7][r]);
            *(uint4*)&myFA[slotAddr(lnm, qu * 4 + r)] = ua;
            ub.x = pkbf(accB[0][r], accB[1][r]);
            ub.y = pkbf(accB[2][r], accB[3][r]);
            ub.z = pkbf(accB[4][r], accB[5][r]);
            ub.w = pkbf(accB[6][r], accB[7][r]);
            *(uint4*)&myFB[slotAddr(lnm, qu * 4 + r)] = ub;
        }

        // layer 2 dual MFMA (WF2 staged with matching k-permutation)
        #pragma unroll
        for (int c = 0; c < 8; ++c) {
            accA[c] = (float4v){0.f, 0.f, 0.f, 0.f};
            accB[c] = (float4v){0.f, 0.f, 0.f, 0.f};
        }
        #pragma unroll
        for (int s = 0; s < 4; ++s) {
            short8 afA = *(const short8*)&myFA[slotAddr(s * 4 + qu, lnm)];
            short8 afB = *(const short8*)&myFB[slotAddr(s * 4 + qu, lnm)];
            #pragma unroll
            for (int c = 0; c < 8; ++c) {
                short8 bfv = *(const short8*)&WF2[((c * 4 + s) * 64 + lane) * 8];
                accA[c] = __builtin_amdgcn_mfma_f32_16x16x32_bf16(afA, bfv, accA[c], 0, 0, 0);
                accB[c] = __builtin_amdgcn_mfma_f32_16x16x32_bf16(afB, bfv, accB[c], 0, 0, 0);
            }
        }
        ln_elu2(accA, accB, PIf + 512, lnm);

        // pack q2 -> afcA[2,3]; issue q3 (next-B half1; packs after stores)
        if (pn < npairs) {
            afcA[2] = packfrag(xf[0], xf[1]);
            afcA[3] = packfrag(xf[2], xf[3]);
            xf[0] = *(const float4v*)(xrB + 0);
            xf[1] = *(const float4v*)(xrB + 4);
            xf[2] = *(const float4v*)(xrB + 32);
            xf[3] = *(const float4v*)(xrB + 36);
        }

        // store h2 from registers, permuted feature layout; strips 2p,2p+1
        // are 32 contiguous rows -> stores coalesce across the pair.
        const size_t rowA = (size_t)(2 * pair) * 16;
        #pragma unroll
        for (int r = 0; r < 4; ++r) {
            uint4 ua, ub;
            ua.x = pkbf(accA[0][r], accA[1][r]);
            ua.y = pkbf(accA[2][r], accA[3][r]);
            ua.z = pkbf(accA[4][r], accA[5][r]);
            ua.w = pkbf(accA[6][r], accA[7][r]);
            *(uint4*)(h2out + (rowA + qu * 4 + r) * NF + lnm * 8) = ua;
            ub.x = pkbf(accB[0][r], accB[1][r]);
            ub.y = pkbf(accB[2][r], accB[3][r]);
            ub.z = pkbf(accB[4][r], accB[5][r]);
            ub.w = pkbf(accB[6][r], accB[7][r]);
            *(uint4*)(h2out + (rowA + 16 + qu * 4 + r) * NF + lnm * 8) = ub;
        }

        // pack q3 -> afcB[0,1]; issue q4 (next-B half2); pack q4 last
        // (~300 cy exposed vmcnt wait, ~5% of pair time — accepted).
        if (pn < npairs) {
            afcB[0] = packfrag(xf[0], xf[1]);
            afcB[1] = packfrag(xf[2], xf[3]);
            xf[0] = *(const float4v*)(xrB + 64);
            xf[1] = *(const float4v*)(xrB + 68);
            xf[2] = *(const float4v*)(xrB + 96);
            xf[3] = *(const float4v*)(xrB + 100);
            afcB[2] = packfrag(xf[0], xf[1]);
            afcB[3] = packfrag(xf[2], xf[3]);
        }
    }
}

// ---------------- edge kernel ----------------
// h2 is in permuted feature layout; Wr1 staged with the same k-permutation.
// 512-thread blocks (8 waves), verified r10 config. LDS carve (shorts):
//   WFr [0,16384) | MYF [16384,16384+8*2048) | PI at 32768 shorts
#define E_MYF   16384
#define E_PI    32768
#define E_TOT   (32768 + 1024)          // shorts -> 67584 B

__global__ __launch_bounds__(512, 2)
void edge_kernel(const unsigned short* __restrict__ h2,
                 const int* __restrict__ pidx,
                 const float* __restrict__ Wr1, const float* __restrict__ br1,
                 const float* __restrict__ gr1, const float* __restrict__ ber1,
                 const float* __restrict__ Wr2, const float* __restrict__ br2,
                 float* __restrict__ rout)
{
    __shared__ __align__(16) unsigned short SH[E_TOT];

    const int tid  = threadIdx.x;
    const int lane = tid & 63;
    const int wave = tid >> 6;        // 0..7
    const int lnm  = lane & 15;
    const int qu   = lane >> 4;

    stage_wfrags<true, 512>(Wr1, &SH[0], tid);
    float* PIf = (float*)&SH[E_PI];
    if (tid < NF) {
        PIf[tid * 4 + 0] = br1[tid]; PIf[tid * 4 + 1] = gr1[tid];
        PIf[tid * 4 + 2] = ber1[tid];
    }

    float w2c[8];
    #pragma unroll
    for (int c = 0; c < 8; ++c) w2c[c] = Wr2[c * 16 + lnm];
    const float br2v = br2[0];

    unsigned short* myF = &SH[E_MYF + wave * 2048];
    const unsigned short* WFr = &SH[0];

    const int nstrips = NEDGE / 16;          // 16380
    const int sstep   = gridDim.x * 8;       // 2048
    const int s0      = blockIdx.x * 8 + wave;

    short8 cv[4], pv[4];
    int prn[4];
    if (s0 < nstrips) {
        int pr[4];
        #pragma unroll
        for (int t = 0; t < 4; ++t) pr[t] = pidx[s0 * 16 + t * 4 + qu];
        #pragma unroll
        for (int t = 0; t < 4; ++t) {
            int e = s0 * 16 + t * 4 + qu;
            int crow = e + (int)((unsigned)e / 4095u);
            cv[t] = *(const short8*)(h2 + (size_t)crow * NF + lnm * 8);
            pv[t] = *(const short8*)(h2 + (size_t)pr[t] * NF + lnm * 8);
        }
        int s1 = s0 + sstep;
        if (s1 < nstrips) {
            #pragma unroll
            for (int t = 0; t < 4; ++t) prn[t] = pidx[s1 * 16 + t * 4 + qu];
        }
    }
    __syncthreads();

    for (int strip = s0; strip < nstrips; strip += sstep) {
        // max in fp32, pack pairs, one b128 slot write per t
        #pragma unroll
        for (int t = 0; t < 4; ++t) {
            float m0 = fmaxf(bf2f((unsigned short)cv[t][0]), bf2f((unsigned short)pv[t][0]));
            float m1 = fmaxf(bf2f((unsigned short)cv[t][1]), bf2f((unsigned short)pv[t][1]));
            float m2 = fmaxf(bf2f((unsigned short)cv[t][2]), bf2f((unsigned short)pv[t][2]));
            float m3 = fmaxf(bf2f((unsigned short)cv[t][3]), bf2f((unsigned short)pv[t][3]));
            float m4 = fmaxf(bf2f((unsigned short)cv[t][4]), bf2f((unsigned short)pv[t][4]));
            float m5 = fmaxf(bf2f((unsigned short)cv[t][5]), bf2f((unsigned short)pv[t][5]));
            float m6 = fmaxf(bf2f((unsigned short)cv[t][6]), bf2f((unsigned short)pv[t][6]));
            float m7 = fmaxf(bf2f((unsigned short)cv[t][7]), bf2f((unsigned short)pv[t][7]));
            uint4 u;
            u.x = pkbf(m0, m1); u.y = pkbf(m2, m3);
            u.z = pkbf(m4, m5); u.w = pkbf(m6, m7);
            *(uint4*)&myF[slotAddr(lnm, t * 4 + qu)] = u;
        }

        // prefetch next strip's rows (pidx already in prn), pidx two ahead
        int sn = strip + sstep;
        if (sn < nstrips) {
            #pragma unroll
            for (int t = 0; t < 4; ++t) {
                int e = sn * 16 + t * 4 + qu;
                int crow = e + (int)((unsigned)e / 4095u);
                cv[t] = *(const short8*)(h2 + (size_t)crow * NF + lnm * 8);
                pv[t] = *(const short8*)(h2 + (size_t)prn[t] * NF + lnm * 8);
            }
            int sn2 = sn + sstep;
            if (sn2 < nstrips) {
                #pragma unroll
                for (int t = 0; t < 4; ++t) prn[t] = pidx[sn2 * 16 + t * 4 + qu];
            }
        }

        // MFMA + LN/ELU + dot(Wr2)
        float4v acc[8];
        #pragma unroll
        for (int c = 0; c < 8; ++c) acc[c] = (float4v){0.f, 0.f, 0.f, 0.f};
        #pragma unroll
        for (int s = 0; s < 4; ++s) {
            short8 af = *(const short8*)&myF[slotAddr(s * 4 + qu, lnm)];
            #pragma unroll
            for (int c = 0; c < 8; ++c) {
                short8 bfv = *(const short8*)&WFr[((c * 4 + s) * 64 + lane) * 8];
                acc[c] = __builtin_amdgcn_mfma_f32_16x16x32_bf16(af, bfv, acc[c], 0, 0, 0);
            }
        }
        ln_elu(acc, PIf, lnm);

        #pragma unroll
        for (int r = 0; r < 4; ++r) {
            float t2 = 0.f;
            #pragma unroll
            for (int c = 0; c < 8; ++c) t2 += acc[c][r] * w2c[c];
            t2 = red16(t2);
            if (lnm == 0) rout[strip * 16 + qu * 4 + r] = t2 + br2v;
        }
    }
}

__global__ __launch_bounds__(1024)
void lse_kernel(const float* __restrict__ r, float* __restrict__ out)
{
    __shared__ float red[1024];
    const int b = blockIdx.x;
    const float* rb = r + (size_t)b * 4095;

    float mx = -1e30f;
    for (int i = threadIdx.x; i < 4095; i += 1024) mx = fmaxf(mx, rb[i]);
    red[threadIdx.x] = mx;
    __syncthreads();
    for (int s = 512; s > 0; s >>= 1) {
        if (threadIdx.x < s) red[threadIdx.x] = fmaxf(red[threadIdx.x], red[threadIdx.x + s]);
        __syncthreads();
    }
    mx = red[0];
    __syncthreads();

    float sum = 0.f;
    for (int i = threadIdx.x; i < 4095; i += 1024) sum += __expf(rb[i] - mx);
    red[threadIdx.x] = sum;
    __syncthreads();
    for (int s = 512; s > 0; s >>= 1) {
        if (threadIdx.x < s) red[threadIdx.x] += red[threadIdx.x + s];
        __syncthreads();
    }
    float lse = mx + __logf(red[0]);

    for (int i = threadIdx.x; i < 4095; i += 1024)
        out[(size_t)b * 4095 + i] = rb[i] - lse;
}

extern "C" void kernel_launch(void* const* d_in, const int* in_sizes, int n_in,
                              void* d_out, int out_size, void* d_ws, size_t ws_size,
                              hipStream_t stream)
{
    const float* x    = (const float*)d_in[0];
    const int*   pidx = (const int*)d_in[1];
    const float* W1   = (const float*)d_in[2];
    const float* b1   = (const float*)d_in[3];
    const float* g1   = (const float*)d_in[4];
    const float* be1  = (const float*)d_in[5];
    const float* W2   = (const float*)d_in[6];
    const float* b2   = (const float*)d_in[7];
    const float* g2   = (const float*)d_in[8];
    const float* be2  = (const float*)d_in[9];
    const float* Wr1  = (const float*)d_in[10];
    const float* br1  = (const float*)d_in[11];
    const float* gr1  = (const float*)d_in[12];
    const float* ber1 = (const float*)d_in[13];
    const float* Wr2  = (const float*)d_in[14];
    const float* br2  = (const float*)d_in[15];
    float* out = (float*)d_out;

    // workspace: h2 (bf16, 64 MiB, permuted feature layout) | rbuf (fp32)
    unsigned short* h2 = (unsigned short*)d_ws;
    float* rbuf = (float*)(h2 + (size_t)MROWS * NF);

    fused12_kernel<<<256, 512, 0, stream>>>(x, W1, b1, g1, be1,
                                            W2, b2, g2, be2, h2);
    edge_kernel<<<256, 512, 0, stream>>>(h2, pidx, Wr1, br1, gr1, ber1,
                                         Wr2, br2, rbuf);
    lse_kernel<<<BATCH, 1024, 0, stream>>>(rbuf, out);
}

// Round 11
// 102.501 us; speedup vs baseline: 1.1878x; 1.0018x over previous
//
#include <hip/hip_runtime.h>
#include <hip/hip_bf16.h>

#define NF     128
#define BATCH  64
#define NNODES 4096
#define MROWS  (BATCH * NNODES)       // 262144
#define NEDGE  (BATCH * (NNODES - 1)) // 262080
#define LN_EPS 1e-5f

typedef short  short8  __attribute__((ext_vector_type(8)));
typedef float  float4v __attribute__((ext_vector_type(4)));

__device__ __forceinline__ unsigned short f2bf(float f) {
    union { float f; unsigned u; } v; v.f = f;
    unsigned r = v.u;
    r = r + 0x7FFF + ((r >> 16) & 1);   // RNE
    return (unsigned short)(r >> 16);
}
__device__ __forceinline__ float bf2f(unsigned short b) {
    union { unsigned u; float f; } v; v.u = ((unsigned)b) << 16;
    return v.f;
}
// packed f32x2 -> bf16x2 (v_cvt_pk_bf16_f32), low short = lo. RNE == f2bf.
__device__ __forceinline__ unsigned pkbf(float lo, float hi) {
    __hip_bfloat162 h = __float22bfloat162_rn(float2{lo, hi});
    union { __hip_bfloat162 h; unsigned u; } v; v.h = h;
    return v.u;
}
// 8 fp32 -> one A-fragment octet (short8 of bf16); layout verified r7/r12.
__device__ __forceinline__ short8 packfrag(float4v a, float4v b) {
    union { short8 s; unsigned u[4]; } v;
    v.u[0] = pkbf(a[0], a[1]); v.u[1] = pkbf(a[2], a[3]);
    v.u[2] = pkbf(b[0], b[1]); v.u[3] = pkbf(b[2], b[3]);
    return v.s;
}

// DPP 16-lane sum (VALU pipe, no LDS). Exact for aligned 16-lane groups.
template <int CTRL>
__device__ __forceinline__ float dppadd(float v) {
    union { float f; int i; } a, b; a.f = v;
    b.i = __builtin_amdgcn_mov_dpp(a.i, CTRL, 0xF, 0xF, true);
    return v + b.f;
}
__device__ __forceinline__ float red16(float v) {
    v = dppadd<0xB1>(v);    // quad_perm ^1
    v = dppadd<0x4E>(v);    // quad_perm ^2
    v = dppadd<0x141>(v);   // row_half_mirror (== ^4 after quad-uniform)
    v = dppadd<0x140>(v);   // row_mirror      (== ^8 after half-uniform)
    return v;
}

// A-fragment slot address (shorts): slot(q,m) holds A[m][k-octet q] (16 B).
// XOR swizzle spreads bank groups (validated r4-r6).
__device__ __forceinline__ int slotAddr(int q, int m) {
    return ((q * 16 + m) ^ (q & 7)) * 8;
}

// Stage W (128x128 fp32, k-major) into WF in bf16 MFMA B-fragment order.
// PERM: k-row k is placed at fragment position p=(k&15)*8+(k>>4), matching the
// permuted feature layout n(p)=(p&7)*16+(p>>3) used for h1-slots and h2.
// NT = block size in threads (generic strided loop).
template <bool PERM, int NT>
__device__ __forceinline__ void stage_wfrags(const float* __restrict__ W,
                                             unsigned short* __restrict__ WF,
                                             int tid) {
    for (int g = tid; g < 4096; g += NT) {
        int k  = g >> 5;                  // true input-feature row 0..127
        int n0 = (g & 31) * 4;
        float4v wv = *(const float4v*)(W + k * NF + n0);
        int p = PERM ? ((k & 15) * 8 + (k >> 4)) : k;
        int s = p >> 5, q = (p & 31) >> 3, j = p & 7;
        #pragma unroll
        for (int e = 0; e < 4; ++e) {
            int n = n0 + e;
            WF[((((n >> 4) * 4 + s) * 64) + q * 16 + (n & 15)) * 8 + j] = f2bf(wv[e]);
        }
    }
}

// bias + LayerNorm(128) + ELU on C-layout accumulators.
// PI: interleaved params PI[n*4 + {0:bias,1:gain,2:beta}] (stride-4 floats).
// r6-VERIFIED form. r8 (3-pass) and r15 (packed-f32) rewrites BOTH failed
// correctness for unexplained reasons — DO NOT restructure this function.
__device__ __forceinline__ void ln_elu(float4v acc[8], const float* __restrict__ PI,
                                       int lnm) {
    float bias[8], gn[8], bt[8];
    #pragma unroll
    for (int c = 0; c < 8; ++c) {
        float4v prm = *(const float4v*)&PI[(c * 16 + lnm) * 4];
        bias[c] = prm[0]; gn[c] = prm[1]; bt[c] = prm[2];
    }
    #pragma unroll
    for (int r = 0; r < 4; ++r) {
        float s1 = 0.f, s2 = 0.f;
        #pragma unroll
        for (int c = 0; c < 8; ++c) {
            float t = acc[c][r] + bias[c];
            acc[c][r] = t;
            s1 += t; s2 += t * t;
        }
        s1 = red16(s1);
        s2 = red16(s2);
        float mu  = s1 * (1.0f / 128.0f);
        float var = s2 * (1.0f / 128.0f) - mu * mu;
        float rs  = rsqrtf(var + LN_EPS);
        #pragma unroll
        for (int c = 0; c < 8; ++c) {
            float y = (acc[c][r] - mu) * rs * gn[c] + bt[c];
            acc[c][r] = (y > 0.f) ? y : (__expf(y) - 1.0f);
        }
    }
}

// Dual-strip LN — r13-VERIFIED (passed absmax 0.125). Same per-element ops
// as ln_elu on each acc set; only the param loads are shared.
__device__ __forceinline__ void ln_elu2(float4v a[8], float4v b[8],
                                        const float* __restrict__ PI, int lnm) {
    float bias[8], gn[8], bt[8];
    #pragma unroll
    for (int c = 0; c < 8; ++c) {
        float4v prm = *(const float4v*)&PI[(c * 16 + lnm) * 4];
        bias[c] = prm[0]; gn[c] = prm[1]; bt[c] = prm[2];
    }
    #pragma unroll
    for (int r = 0; r < 4; ++r) {
        float s1a = 0.f, s2a = 0.f, s1b = 0.f, s2b = 0.f;
        #pragma unroll
        for (int c = 0; c < 8; ++c) {
            float ta = a[c][r] + bias[c];
            a[c][r] = ta; s1a += ta; s2a += ta * ta;
            float tb = b[c][r] + bias[c];
            b[c][r] = tb; s1b += tb; s2b += tb * tb;
        }
        s1a = red16(s1a); s2a = red16(s2a);
        s1b = red16(s1b); s2b = red16(s2b);
        float mua = s1a * (1.0f / 128.0f);
        float vara = s2a * (1.0f / 128.0f) - mua * mua;
        float rsa = rsqrtf(vara + LN_EPS);
        float mub = s1b * (1.0f / 128.0f);
        float varb = s2b * (1.0f / 128.0f) - mub * mub;
        float rsb = rsqrtf(varb + LN_EPS);
        #pragma unroll
        for (int c = 0; c < 8; ++c) {
            float ya = (a[c][r] - mua) * rsa * gn[c] + bt[c];
            a[c][r] = (ya > 0.f) ? ya : (__expf(ya) - 1.0f);
            float yb = (b[c][r] - mub) * rsb * gn[c] + bt[c];
            b[c][r] = (yb > 0.f) ? yb : (__expf(yb) - 1.0f);
        }
    }
}

// ---------------- fused layer1+layer2 ----------------
// r16: dual-strip ILP (r13 structure, correctness-verified) + quartered
// prefetch through ONE xf[4] buffer (r14 trick, spill-free-verified).
// 512 threads (8 waves, (512,2) config). LDS carve (shorts):
//   WF1 [0,16384) | WF2 [16384,32768) | MYF [32768, 32768+8*4096) |
//   PI (floats) at 65536: 2 sets x 512 floats
#define F_MYF   32768
#define F_PI    65536
#define F_TOT   (65536 + 2048)          // shorts -> 135168 B

// History: (512,2) = 256 unified VGPR/wave, split ~50/50 arch/acc.
// r13 dual-strip passed correctness but spilled (xfA+xfB = 64 arch fp32
// prefetch regs -> 130+ arch > 128). r16 replaces that with the r14
// quartered schedule: 4 load-quarters (4 float4 each) rotate through one
// xf[4] (16 regs), each packed to bf16 one major phase after issue.
// Arch peak ~110 < 128; acc = accA+accB = 64 < 128. Win mechanism: each
// WF B-fragment ds_read feeds 2 MFMAs; two independent LN chains overlap;
// LN params amortize; strips 2p/2p+1 contiguous for x-loads and h2 stores.
__global__ __launch_bounds__(512, 2)
void fused12_kernel(const float* __restrict__ x,
                    const float* __restrict__ W1, const float* __restrict__ b1,
                    const float* __restrict__ g1, const float* __restrict__ be1,
                    const float* __restrict__ W2, const float* __restrict__ b2,
                    const float* __restrict__ g2, const float* __restrict__ be2,
                    unsigned short* __restrict__ h2out)
{
    __shared__ __align__(16) unsigned short SH[F_TOT];

    const int tid  = threadIdx.x;
    const int lane = tid & 63;
    const int wave = tid >> 6;        // 0..7
    const int lnm  = lane & 15;
    const int qu   = lane >> 4;

    stage_wfrags<false, 512>(W1, &SH[0], tid);
    stage_wfrags<true , 512>(W2, &SH[16384], tid);
    float* PIf = (float*)&SH[F_PI];
    if (tid < NF) {
        PIf[tid * 4 + 0] = b1[tid]; PIf[tid * 4 + 1] = g1[tid]; PIf[tid * 4 + 2] = be1[tid];
        PIf[512 + tid * 4 + 0] = b2[tid]; PIf[512 + tid * 4 + 1] = g2[tid];
        PIf[512 + tid * 4 + 2] = be2[tid];
    }

    unsigned short* myFA = &SH[F_MYF + wave * 4096];
    unsigned short* myFB = myFA + 2048;
    const unsigned short* WF1 = &SH[0];
    const unsigned short* WF2 = &SH[16384];

    const int npairs = MROWS / 32;           // 8192 strip-pairs
    const int pstep  = gridDim.x * 8;        // 2048
    int pair = blockIdx.x * 8 + wave;

    // fragment-order x loads (r12-verified): lane (qu,lnm) reads row lnm,
    // float octet s*4+qu -> base + s*32 (+4).
    const int laneOff = lnm * NF + qu * 8;

    float4v xf[4];
    short8  afcA[4], afcB[4];
    if (pair < npairs) {
        const float* xrA = x + (size_t)(2 * pair) * (16 * NF) + laneOff;
        const float* xrB = xrA + 16 * NF;
        xf[0] = *(const float4v*)(xrA + 0);
        xf[1] = *(const float4v*)(xrA + 4);
        xf[2] = *(const float4v*)(xrA + 32);
        xf[3] = *(const float4v*)(xrA + 36);
        afcA[0] = packfrag(xf[0], xf[1]);
        afcA[1] = packfrag(xf[2], xf[3]);
        xf[0] = *(const float4v*)(xrA + 64);
        xf[1] = *(const float4v*)(xrA + 68);
        xf[2] = *(const float4v*)(xrA + 96);
        xf[3] = *(const float4v*)(xrA + 100);
        afcA[2] = packfrag(xf[0], xf[1]);
        afcA[3] = packfrag(xf[2], xf[3]);
        xf[0] = *(const float4v*)(xrB + 0);
        xf[1] = *(const float4v*)(xrB + 4);
        xf[2] = *(const float4v*)(xrB + 32);
        xf[3] = *(const float4v*)(xrB + 36);
        afcB[0] = packfrag(xf[0], xf[1]);
        afcB[1] = packfrag(xf[2], xf[3]);
        xf[0] = *(const float4v*)(xrB + 64);
        xf[1] = *(const float4v*)(xrB + 68);
        xf[2] = *(const float4v*)(xrB + 96);
        xf[3] = *(const float4v*)(xrB + 100);
        afcB[2] = packfrag(xf[0], xf[1]);
        afcB[3] = packfrag(xf[2], xf[3]);
    }
    __syncthreads();

    for (; pair < npairs; pair += pstep) {
        int pn = pair + pstep;
        const float* xrA = x + (size_t)(2 * pn) * (16 * NF) + laneOff;
        const float* xrB = xrA + 16 * NF;

        // (q1) issue next-A half1 (packs after LN1; ~2700 cy to land)
        if (pn < npairs) {
            xf[0] = *(const float4v*)(xrA + 0);
            xf[1] = *(const float4v*)(xrA + 4);
            xf[2] = *(const float4v*)(xrA + 32);
            xf[3] = *(const float4v*)(xrA + 36);
        }

        // layer 1 dual MFMA: each B-fragment read feeds both strips
        float4v accA[8], accB[8];
        #pragma unroll
        for (int c = 0; c < 8; ++c) {
            accA[c] = (float4v){0.f, 0.f, 0.f, 0.f};
            accB[c] = (float4v){0.f, 0.f, 0.f, 0.f};
        }
        #pragma unroll
        for (int s = 0; s < 4; ++s) {
            #pragma unroll
            for (int c = 0; c < 8; ++c) {
                short8 bfv = *(const short8*)&WF1[((c * 4 + s) * 64 + lane) * 8];
                accA[c] = __builtin_amdgcn_mfma_f32_16x16x32_bf16(afcA[s], bfv, accA[c], 0, 0, 0);
                accB[c] = __builtin_amdgcn_mfma_f32_16x16x32_bf16(afcB[s], bfv, accB[c], 0, 0, 0);
            }
        }
        ln_elu2(accA, accB, PIf, lnm);

        // pack q1 -> afcA[0,1] (old afcA consumed by L1); issue q2 (next-A
        // half2; packs after L2, ~1900 cy to land)
        if (pn < npairs) {
            afcA[0] = packfrag(xf[0], xf[1]);
            afcA[1] = packfrag(xf[2], xf[3]);
            xf[0] = *(const float4v*)(xrA + 64);
            xf[1] = *(const float4v*)(xrA + 68);
            xf[2] = *(const float4v*)(xrA + 96);
            xf[3] = *(const float4v*)(xrA + 100);
        }

        // L2 repack in PERMUTED feature order (one b128 per r per strip)
        #pragma unroll
        for (int r = 0; r < 4; ++r) {
            uint4 ua, ub;
            ua.x = pkbf(accA[0][r], accA[1][r]);
            ua.y = pkbf(accA[2][r], accA[3][r]);
            ua.z = pkbf(accA[4][r], accA[5][r]);
            ua.w = pkbf(accA[6][r], accA[7][r]);
            *(uint4*)&myFA[slotAddr(lnm, qu * 4 + r)] = ua;
            ub.x = pkbf(accB[0][r], accB[1][r]);
            ub.y = pkbf(accB[2][r], accB[3][r]);
            ub.z = pkbf(accB[4][r], accB[5][r]);
            ub.w = pkbf(accB[6][r], accB[7][r]);
            *(uint4*)&myFB[slotAddr(lnm, qu * 4 + r)] = ub;
        }

        // layer 2 dual MFMA (WF2 staged with matching k-permutation)
        #pragma unroll
        for (int c = 0; c < 8; ++c) {
            accA[c] = (float4v){0.f, 0.f, 0.f, 0.f};
            accB[c] = (float4v){0.f, 0.f, 0.f, 0.f};
        }
        #pragma unroll
        for (int s = 0; s < 4; ++s) {
            short8 afA = *(const short8*)&myFA[slotAddr(s * 4 + qu, lnm)];
            short8 afB = *(const short8*)&myFB[slotAddr(s * 4 + qu, lnm)];
            #pragma unroll
            for (int c = 0; c < 8; ++c) {
                short8 bfv = *(const short8*)&WF2[((c * 4 + s) * 64 + lane) * 8];
                accA[c] = __builtin_amdgcn_mfma_f32_16x16x32_bf16(afA, bfv, accA[c], 0, 0, 0);
                accB[c] = __builtin_amdgcn_mfma_f32_16x16x32_bf16(afB, bfv, accB[c], 0, 0, 0);
            }
        }
        ln_elu2(accA, accB, PIf + 512, lnm);

        // pack q2 -> afcA[2,3]; issue q3 (next-B half1; packs after stores)
        if (pn < npairs) {
            afcA[2] = packfrag(xf[0], xf[1]);
            afcA[3] = packfrag(xf[2], xf[3]);
            xf[0] = *(const float4v*)(xrB + 0);
            xf[1] = *(const float4v*)(xrB + 4);
            xf[2] = *(const float4v*)(xrB + 32);
            xf[3] = *(const float4v*)(xrB + 36);
        }

        // store h2 from registers, permuted feature layout; strips 2p,2p+1
        // are 32 contiguous rows -> stores coalesce across the pair.
        const size_t rowA = (size_t)(2 * pair) * 16;
        #pragma unroll
        for (int r = 0; r < 4; ++r) {
            uint4 ua, ub;
            ua.x = pkbf(accA[0][r], accA[1][r]);
            ua.y = pkbf(accA[2][r], accA[3][r]);
            ua.z = pkbf(accA[4][r], accA[5][r]);
            ua.w = pkbf(accA[6][r], accA[7][r]);
            *(uint4*)(h2out + (rowA + qu * 4 + r) * NF + lnm * 8) = ua;
            ub.x = pkbf(accB[0][r], accB[1][r]);
            ub.y = pkbf(accB[2][r], accB[3][r]);
            ub.z = pkbf(accB[4][r], accB[5][r]);
            ub.w = pkbf(accB[6][r], accB[7][r]);
            *(uint4*)(h2out + (rowA + 16 + qu * 4 + r) * NF + lnm * 8) = ub;
        }

        // pack q3 -> afcB[0,1]; issue q4 (next-B half2); pack q4 last
        // (~300 cy exposed vmcnt wait, ~5% of pair time — accepted).
        if (pn < npairs) {
            afcB[0] = packfrag(xf[0], xf[1]);
            afcB[1] = packfrag(xf[2], xf[3]);
            xf[0] = *(const float4v*)(xrB + 64);
            xf[1] = *(const float4v*)(xrB + 68);
            xf[2] = *(const float4v*)(xrB + 96);
            xf[3] = *(const float4v*)(xrB + 100);
            afcB[2] = packfrag(xf[0], xf[1]);
            afcB[3] = packfrag(xf[2], xf[3]);
        }
    }
}

// ---------------- edge kernel ----------------
// h2 is in permuted feature layout; Wr1 staged with the same k-permutation.
// 512-thread blocks (8 waves), verified r10 config. LDS carve (shorts):
//   WFr [0,16384) | MYF [16384,16384+8*2048) | PI at 32768 shorts
#define E_MYF   16384
#define E_PI    32768
#define E_TOT   (32768 + 1024)          // shorts -> 67584 B

__global__ __launch_bounds__(512, 2)
void edge_kernel(const unsigned short* __restrict__ h2,
                 const int* __restrict__ pidx,
                 const float* __restrict__ Wr1, const float* __restrict__ br1,
                 const float* __restrict__ gr1, const float* __restrict__ ber1,
                 const float* __restrict__ Wr2, const float* __restrict__ br2,
                 float* __restrict__ rout)
{
    __shared__ __align__(16) unsigned short SH[E_TOT];

    const int tid  = threadIdx.x;
    const int lane = tid & 63;
    const int wave = tid >> 6;        // 0..7
    const int lnm  = lane & 15;
    const int qu   = lane >> 4;

    stage_wfrags<true, 512>(Wr1, &SH[0], tid);
    float* PIf = (float*)&SH[E_PI];
    if (tid < NF) {
        PIf[tid * 4 + 0] = br1[tid]; PIf[tid * 4 + 1] = gr1[tid];
        PIf[tid * 4 + 2] = ber1[tid];
    }

    float w2c[8];
    #pragma unroll
    for (int c = 0; c < 8; ++c) w2c[c] = Wr2[c * 16 + lnm];
    const float br2v = br2[0];

    unsigned short* myF = &SH[E_MYF + wave * 2048];
    const unsigned short* WFr = &SH[0];

    const int nstrips = NEDGE / 16;          // 16380
    const int sstep   = gridDim.x * 8;       // 2048
    const int s0      = blockIdx.x * 8 + wave;

    short8 cv[4], pv[4];
    int prn[4];
    if (s0 < nstrips) {
        int pr[4];
        #pragma unroll
        for (int t = 0; t < 4; ++t) pr[t] = pidx[s0 * 16 + t * 4 + qu];
        #pragma unroll
        for (int t = 0; t < 4; ++t) {
            int e = s0 * 16 + t * 4 + qu;
            int crow = e + (int)((unsigned)e / 4095u);
            cv[t] = *(const short8*)(h2 + (size_t)crow * NF + lnm * 8);
            pv[t] = *(const short8*)(h2 + (size_t)pr[t] * NF + lnm * 8);
        }
        int s1 = s0 + sstep;
        if (s1 < nstrips) {
            #pragma unroll
            for (int t = 0; t < 4; ++t) prn[t] = pidx[s1 * 16 + t * 4 + qu];
        }
    }
    __syncthreads();

    for (int strip = s0; strip < nstrips; strip += sstep) {
        // max in fp32, pack pairs, one b128 slot write per t
        #pragma unroll
        for (int t = 0; t < 4; ++t) {
            float m0 = fmaxf(bf2f((unsigned short)cv[t][0]), bf2f((unsigned short)pv[t][0]));
            float m1 = fmaxf(bf2f((unsigned short)cv[t][1]), bf2f((unsigned short)pv[t][1]));
            float m2 = fmaxf(bf2f((unsigned short)cv[t][2]), bf2f((unsigned short)pv[t][2]));
            float m3 = fmaxf(bf2f((unsigned short)cv[t][3]), bf2f((unsigned short)pv[t][3]));
            float m4 = fmaxf(bf2f((unsigned short)cv[t][4]), bf2f((unsigned short)pv[t][4]));
            float m5 = fmaxf(bf2f((unsigned short)cv[t][5]), bf2f((unsigned short)pv[t][5]));
            float m6 = fmaxf(bf2f((unsigned short)cv[t][6]), bf2f((unsigned short)pv[t][6]));
            float m7 = fmaxf(bf2f((unsigned short)cv[t][7]), bf2f((unsigned short)pv[t][7]));
            uint4 u;
            u.x = pkbf(m0, m1); u.y = pkbf(m2, m3);
            u.z = pkbf(m4, m5); u.w = pkbf(m6, m7);
            *(uint4*)&myF[slotAddr(lnm, t * 4 + qu)] = u;
        }

        // prefetch next strip's rows (pidx already in prn), pidx two ahead
        int sn = strip + sstep;
        if (sn < nstrips) {
            #pragma unroll
            for (int t = 0; t < 4; ++t) {
                int e = sn * 16 + t * 4 + qu;
                int crow = e + (int)((unsigned)e / 4095u);
                cv[t] = *(const short8*)(h2 + (size_t)crow * NF + lnm * 8);
                pv[t] = *(const short8*)(h2 + (size_t)prn[t] * NF + lnm * 8);
            }
            int sn2 = sn + sstep;
            if (sn2 < nstrips) {
                #pragma unroll
                for (int t = 0; t < 4; ++t) prn[t] = pidx[sn2 * 16 + t * 4 + qu];
            }
        }

        // MFMA + LN/ELU + dot(Wr2)
        float4v acc[8];
        #pragma unroll
        for (int c = 0; c < 8; ++c) acc[c] = (float4v){0.f, 0.f, 0.f, 0.f};
        #pragma unroll
        for (int s = 0; s < 4; ++s) {
            short8 af = *(const short8*)&myF[slotAddr(s * 4 + qu, lnm)];
            #pragma unroll
            for (int c = 0; c < 8; ++c) {
                short8 bfv = *(const short8*)&WFr[((c * 4 + s) * 64 + lane) * 8];
                acc[c] = __builtin_amdgcn_mfma_f32_16x16x32_bf16(af, bfv, acc[c], 0, 0, 0);
            }
        }
        ln_elu(acc, PIf, lnm);

        #pragma unroll
        for (int r = 0; r < 4; ++r) {
            float t2 = 0.f;
            #pragma unroll
            for (int c = 0; c < 8; ++c) t2 += acc[c][r] * w2c[c];
            t2 = red16(t2);
            if (lnm == 0) rout[strip * 16 + qu * 4 + r] = t2 + br2v;
        }
    }
}

__global__ __launch_bounds__(1024)
void lse_kernel(const float* __restrict__ r, float* __restrict__ out)
{
    __shared__ float red[1024];
    const int b = blockIdx.x;
    const float* rb = r + (size_t)b * 4095;

    float mx = -1e30f;
    for (int i = threadIdx.x; i < 4095; i += 1024) mx = fmaxf(mx, rb[i]);
    red[threadIdx.x] = mx;
    __syncthreads();
    for (int s = 512; s > 0; s >>= 1) {
        if (threadIdx.x < s) red[threadIdx.x] = fmaxf(red[threadIdx.x], red[threadIdx.x + s]);
        __syncthreads();
    }
    mx = red[0];
    __syncthreads();

    float sum = 0.f;
    for (int i = threadIdx.x; i < 4095; i += 1024) sum += __expf(rb[i] - mx);
    red[threadIdx.x] = sum;
    __syncthreads();
    for (int s = 512; s > 0; s >>= 1) {
        if (threadIdx.x < s) red[threadIdx.x] += red[threadIdx.x + s];
        __syncthreads();
    }
    float lse = mx + __logf(red[0]);

    for (int i = threadIdx.x; i < 4095; i += 1024)
        out[(size_t)b * 4095 + i] = rb[i] - lse;
}

extern "C" void kernel_launch(void* const* d_in, const int* in_sizes, int n_in,
                              void* d_out, int out_size, void* d_ws, size_t ws_size,
                              hipStream_t stream)
{
    const float* x    = (const float*)d_in[0];
    const int*   pidx = (const int*)d_in[1];
    const float* W1   = (const float*)d_in[2];
    const float* b1   = (const float*)d_in[3];
    const float* g1   = (const float*)d_in[4];
    const float* be1  = (const float*)d_in[5];
    const float* W2   = (const float*)d_in[6];
    const float* b2   = (const float*)d_in[7];
    const float* g2   = (const float*)d_in[8];
    const float* be2  = (const float*)d_in[9];
    const float* Wr1  = (const float*)d_in[10];
    const float* br1  = (const float*)d_in[11];
    const float* gr1  = (const float*)d_in[12];
    const float* ber1 = (const float*)d_in[13];
    const float* Wr2  = (const float*)d_in[14];
    const float* br2  = (const float*)d_in[15];
    float* out = (float*)d_out;

    // workspace: h2 (bf16, 64 MiB, permuted feature layout) | rbuf (fp32)
    unsigned short* h2 = (unsigned short*)d_ws;
    float* rbuf = (float*)(h2 + (size_t)MROWS * NF);

    fused12_kernel<<<256, 512, 0, stream>>>(x, W1, b1, g1, be1,
                                            W2, b2, g2, be2, h2);
    edge_kernel<<<256, 512, 0, stream>>>(h2, pidx, Wr1, br1, gr1, ber1,
                                         Wr2, br2, rbuf);
    lse_kernel<<<BATCH, 1024, 0, stream>>>(rbuf, out);
}

// Round 12
// 101.604 us; speedup vs baseline: 1.1983x; 1.0088x over previous
//
#include <hip/hip_runtime.h>
#include <hip/hip_bf16.h>

#define NF     128
#define BATCH  64
#define NNODES 4096
#define MROWS  (BATCH * NNODES)       // 262144
#define NEDGE  (BATCH * (NNODES - 1)) // 262080
#define LN_EPS 1e-5f

typedef short  short8  __attribute__((ext_vector_type(8)));
typedef float  float4v __attribute__((ext_vector_type(4)));

__device__ __forceinline__ unsigned short f2bf(float f) {
    union { float f; unsigned u; } v; v.f = f;
    unsigned r = v.u;
    r = r + 0x7FFF + ((r >> 16) & 1);   // RNE
    return (unsigned short)(r >> 16);
}
__device__ __forceinline__ float bf2f(unsigned short b) {
    union { unsigned u; float f; } v; v.u = ((unsigned)b) << 16;
    return v.f;
}
// packed f32x2 -> bf16x2 (v_cvt_pk_bf16_f32), low short = lo. RNE == f2bf.
__device__ __forceinline__ unsigned pkbf(float lo, float hi) {
    __hip_bfloat162 h = __float22bfloat162_rn(float2{lo, hi});
    union { __hip_bfloat162 h; unsigned u; } v; v.h = h;
    return v.u;
}
// 8 fp32 -> one A-fragment octet (short8 of bf16); layout verified r7/r12.
__device__ __forceinline__ short8 packfrag(float4v a, float4v b) {
    union { short8 s; unsigned u[4]; } v;
    v.u[0] = pkbf(a[0], a[1]); v.u[1] = pkbf(a[2], a[3]);
    v.u[2] = pkbf(b[0], b[1]); v.u[3] = pkbf(b[2], b[3]);
    return v.s;
}

// DPP 16-lane sum (VALU pipe, no LDS). Exact for aligned 16-lane groups.
template <int CTRL>
__device__ __forceinline__ float dppadd(float v) {
    union { float f; int i; } a, b; a.f = v;
    b.i = __builtin_amdgcn_mov_dpp(a.i, CTRL, 0xF, 0xF, true);
    return v + b.f;
}
__device__ __forceinline__ float red16(float v) {
    v = dppadd<0xB1>(v);    // quad_perm ^1
    v = dppadd<0x4E>(v);    // quad_perm ^2
    v = dppadd<0x141>(v);   // row_half_mirror (== ^4 after quad-uniform)
    v = dppadd<0x140>(v);   // row_mirror      (== ^8 after half-uniform)
    return v;
}

// A-fragment slot address (shorts): slot(q,m) holds A[m][k-octet q] (16 B).
// XOR swizzle spreads bank groups (validated r4-r6).
__device__ __forceinline__ int slotAddr(int q, int m) {
    return ((q * 16 + m) ^ (q & 7)) * 8;
}

// Stage W (128x128 fp32, k-major) into WF in bf16 MFMA B-fragment order.
// PERM: k-row k is placed at fragment position p=(k&15)*8+(k>>4), matching the
// permuted feature layout n(p)=(p&7)*16+(p>>3) used for h1-slots and h2.
// NT = block size in threads (generic strided loop).
template <bool PERM, int NT>
__device__ __forceinline__ void stage_wfrags(const float* __restrict__ W,
                                             unsigned short* __restrict__ WF,
                                             int tid) {
    for (int g = tid; g < 4096; g += NT) {
        int k  = g >> 5;                  // true input-feature row 0..127
        int n0 = (g & 31) * 4;
        float4v wv = *(const float4v*)(W + k * NF + n0);
        int p = PERM ? ((k & 15) * 8 + (k >> 4)) : k;
        int s = p >> 5, q = (p & 31) >> 3, j = p & 7;
        #pragma unroll
        for (int e = 0; e < 4; ++e) {
            int n = n0 + e;
            WF[((((n >> 4) * 4 + s) * 64) + q * 16 + (n & 15)) * 8 + j] = f2bf(wv[e]);
        }
    }
}

// bias + LayerNorm(128) + ELU on C-layout accumulators.
// PI: interleaved params PI[n*4 + {0:bias,1:gain,2:beta}] (stride-4 floats).
// r6-VERIFIED form. r8 (3-pass) and r15 (packed-f32) rewrites BOTH failed
// correctness — DO NOT restructure this function.
__device__ __forceinline__ void ln_elu(float4v acc[8], const float* __restrict__ PI,
                                       int lnm) {
    float bias[8], gn[8], bt[8];
    #pragma unroll
    for (int c = 0; c < 8; ++c) {
        float4v prm = *(const float4v*)&PI[(c * 16 + lnm) * 4];
        bias[c] = prm[0]; gn[c] = prm[1]; bt[c] = prm[2];
    }
    #pragma unroll
    for (int r = 0; r < 4; ++r) {
        float s1 = 0.f, s2 = 0.f;
        #pragma unroll
        for (int c = 0; c < 8; ++c) {
            float t = acc[c][r] + bias[c];
            acc[c][r] = t;
            s1 += t; s2 += t * t;
        }
        s1 = red16(s1);
        s2 = red16(s2);
        float mu  = s1 * (1.0f / 128.0f);
        float var = s2 * (1.0f / 128.0f) - mu * mu;
        float rs  = rsqrtf(var + LN_EPS);
        #pragma unroll
        for (int c = 0; c < 8; ++c) {
            float y = (acc[c][r] - mu) * rs * gn[c] + bt[c];
            acc[c][r] = (y > 0.f) ? y : (__expf(y) - 1.0f);
        }
    }
}

// ---------------- fused layer1+layer2 ----------------
// r12-verified structure (FINAL): 512 threads (8 waves, (512,2) config),
// direct fragment-order global loads for layer-1 A (no x LDS round-trip).
// LDS carve (shorts): WF1 [0,16384) | WF2 [16384,32768) |
//   MYF [32768, 32768+8*2048) | PI (floats) at 49152: 2 sets x 512 floats
#define F_MYF   32768
#define F_PI    49152
#define F_TOT   (49152 + 2048)          // shorts -> 102400 B (100 KB)

// SESSION FINDINGS (why this config):
// - Unified VGPR budget splits ~50/50 arch/acc. 1024-thr/4-wave clamps waves
//   to 128 unified -> deterministic scratch spills (WRITE_SIZE 122-155 MB vs
//   the 64 MiB h2 floor). (512,2) -> 256/wave, zero spill, fused12 117->78us.
// - Per-strip time is INVARIANT across 2<->3 waves/SIMD (r12/r14), 1<->2
//   strips/wave ILP (r16), LDS-staged<->direct A (r6/r12): structural
//   plateau, no counter above ~40%. TLP/ILP/staging levers exhausted.
// - ln_elu rewrites (3-pass r8, packed-f32 r15) failed correctness twice;
//   only this scalar form and the r13 ln_elu2 are bench-verified.
__global__ __launch_bounds__(512, 2)
void fused12_kernel(const float* __restrict__ x,
                    const float* __restrict__ W1, const float* __restrict__ b1,
                    const float* __restrict__ g1, const float* __restrict__ be1,
                    const float* __restrict__ W2, const float* __restrict__ b2,
                    const float* __restrict__ g2, const float* __restrict__ be2,
                    unsigned short* __restrict__ h2out)
{
    __shared__ __align__(16) unsigned short SH[F_TOT];

    const int tid  = threadIdx.x;
    const int lane = tid & 63;
    const int wave = tid >> 6;        // 0..7
    const int lnm  = lane & 15;
    const int qu   = lane >> 4;

    stage_wfrags<false, 512>(W1, &SH[0], tid);
    stage_wfrags<true , 512>(W2, &SH[16384], tid);
    float* PIf = (float*)&SH[F_PI];
    if (tid < NF) {
        PIf[tid * 4 + 0] = b1[tid]; PIf[tid * 4 + 1] = g1[tid]; PIf[tid * 4 + 2] = be1[tid];
        PIf[512 + tid * 4 + 0] = b2[tid]; PIf[512 + tid * 4 + 1] = g2[tid];
        PIf[512 + tid * 4 + 2] = be2[tid];
    }

    unsigned short* myF = &SH[F_MYF + wave * 2048];
    const unsigned short* WF1 = &SH[0];
    const unsigned short* WF2 = &SH[16384];

    const int nstrips = MROWS / 16;          // 16384
    const int sstep   = gridDim.x * 8;       // 2048
    int strip = blockIdx.x * 8 + wave;

    // per-lane offset within a strip for fragment-order loads:
    // row lnm, float index (s*4+qu)*8 ..+7 read as two float4 at +s*32(+4)
    const int laneOff = lnm * NF + qu * 8;

    float4v xf[8];
    short8  afc[4];
    if (strip < nstrips) {
        const float* xr = x + (size_t)strip * (16 * NF) + laneOff;
        #pragma unroll
        for (int s = 0; s < 4; ++s) {
            xf[2 * s]     = *(const float4v*)(xr + s * 32);
            xf[2 * s + 1] = *(const float4v*)(xr + s * 32 + 4);
        }
        #pragma unroll
        for (int s = 0; s < 4; ++s) afc[s] = packfrag(xf[2 * s], xf[2 * s + 1]);
    }
    __syncthreads();

    for (; strip < nstrips; strip += sstep) {
        // issue next strip's loads first: in flight through layer1 + LN1
        int sn = strip + sstep;
        if (sn < nstrips) {
            const float* xr = x + (size_t)sn * (16 * NF) + laneOff;
            #pragma unroll
            for (int s = 0; s < 4; ++s) {
                xf[2 * s]     = *(const float4v*)(xr + s * 32);
                xf[2 * s + 1] = *(const float4v*)(xr + s * 32 + 4);
            }
        }

        // layer 1 MFMA: A from registers, B from LDS
        float4v acc[8];
        #pragma unroll
        for (int c = 0; c < 8; ++c) acc[c] = (float4v){0.f, 0.f, 0.f, 0.f};
        #pragma unroll
        for (int s = 0; s < 4; ++s) {
            #pragma unroll
            for (int c = 0; c < 8; ++c) {
                short8 bfv = *(const short8*)&WF1[((c * 4 + s) * 64 + lane) * 8];
                acc[c] = __builtin_amdgcn_mfma_f32_16x16x32_bf16(afc[s], bfv, acc[c], 0, 0, 0);
            }
        }
        ln_elu(acc, PIf, lnm);

        // convert next strip to bf16 frags (loads have had layer1+LN to land;
        // xf dies here -> short live range)
        if (sn < nstrips) {
            #pragma unroll
            for (int s = 0; s < 4; ++s) afc[s] = packfrag(xf[2 * s], xf[2 * s + 1]);
        }

        // L2 repack in PERMUTED feature order: lane's 8 c-values for row
        // m=qu*4+r are contiguous at positions lnm*8..+7 -> one b128 per r.
        // (LDS ops are in-order per wave: these writes can't pass the reads.)
        #pragma unroll
        for (int r = 0; r < 4; ++r) {
            uint4 u;
            u.x = pkbf(acc[0][r], acc[1][r]);
            u.y = pkbf(acc[2][r], acc[3][r]);
            u.z = pkbf(acc[4][r], acc[5][r]);
            u.w = pkbf(acc[6][r], acc[7][r]);
            *(uint4*)&myF[slotAddr(lnm, qu * 4 + r)] = u;
        }

        // layer 2 MFMA (WF2 staged with matching k-permutation)
        #pragma unroll
        for (int c = 0; c < 8; ++c) acc[c] = (float4v){0.f, 0.f, 0.f, 0.f};
        #pragma unroll
        for (int s = 0; s < 4; ++s) {
            short8 af = *(const short8*)&myF[slotAddr(s * 4 + qu, lnm)];
            #pragma unroll
            for (int c = 0; c < 8; ++c) {
                short8 bfv = *(const short8*)&WF2[((c * 4 + s) * 64 + lane) * 8];
                acc[c] = __builtin_amdgcn_mfma_f32_16x16x32_bf16(af, bfv, acc[c], 0, 0, 0);
            }
        }
        ln_elu(acc, PIf + 512, lnm);

        // store h2 DIRECTLY from registers in permuted feature layout:
        // position p=lnm*8+c of row holds feature 16c+lnm. 16 B/lane, rows
        // qu*4+r: 4 fully-covered 256-B segments per instruction.
        const size_t rowBase = (size_t)strip * 16;
        #pragma unroll
        for (int r = 0; r < 4; ++r) {
            uint4 u;
            u.x = pkbf(acc[0][r], acc[1][r]);
            u.y = pkbf(acc[2][r], acc[3][r]);
            u.z = pkbf(acc[4][r], acc[5][r]);
            u.w = pkbf(acc[6][r], acc[7][r]);
            *(uint4*)(h2out + (rowBase + qu * 4 + r) * NF + lnm * 8) = u;
        }
    }
}

// ---------------- edge kernel ----------------
// h2 is in permuted feature layout; Wr1 staged with the same k-permutation.
// 512-thread blocks (8 waves), verified r10 config. LDS carve (shorts):
//   WFr [0,16384) | MYF [16384,16384+8*2048) | PI at 32768 shorts
#define E_MYF   16384
#define E_PI    32768
#define E_TOT   (32768 + 1024)          // shorts -> 67584 B

__global__ __launch_bounds__(512, 2)
void edge_kernel(const unsigned short* __restrict__ h2,
                 const int* __restrict__ pidx,
                 const float* __restrict__ Wr1, const float* __restrict__ br1,
                 const float* __restrict__ gr1, const float* __restrict__ ber1,
                 const float* __restrict__ Wr2, const float* __restrict__ br2,
                 float* __restrict__ rout)
{
    __shared__ __align__(16) unsigned short SH[E_TOT];

    const int tid  = threadIdx.x;
    const int lane = tid & 63;
    const int wave = tid >> 6;        // 0..7
    const int lnm  = lane & 15;
    const int qu   = lane >> 4;

    stage_wfrags<true, 512>(Wr1, &SH[0], tid);
    float* PIf = (float*)&SH[E_PI];
    if (tid < NF) {
        PIf[tid * 4 + 0] = br1[tid]; PIf[tid * 4 + 1] = gr1[tid];
        PIf[tid * 4 + 2] = ber1[tid];
    }

    float w2c[8];
    #pragma unroll
    for (int c = 0; c < 8; ++c) w2c[c] = Wr2[c * 16 + lnm];
    const float br2v = br2[0];

    unsigned short* myF = &SH[E_MYF + wave * 2048];
    const unsigned short* WFr = &SH[0];

    const int nstrips = NEDGE / 16;          // 16380
    const int sstep   = gridDim.x * 8;       // 2048
    const int s0      = blockIdx.x * 8 + wave;

    short8 cv[4], pv[4];
    int prn[4];
    if (s0 < nstrips) {
        int pr[4];
        #pragma unroll
        for (int t = 0; t < 4; ++t) pr[t] = pidx[s0 * 16 + t * 4 + qu];
        #pragma unroll
        for (int t = 0; t < 4; ++t) {
            int e = s0 * 16 + t * 4 + qu;
            int crow = e + (int)((unsigned)e / 4095u);
            cv[t] = *(const short8*)(h2 + (size_t)crow * NF + lnm * 8);
            pv[t] = *(const short8*)(h2 + (size_t)pr[t] * NF + lnm * 8);
        }
        int s1 = s0 + sstep;
        if (s1 < nstrips) {
            #pragma unroll
            for (int t = 0; t < 4; ++t) prn[t] = pidx[s1 * 16 + t * 4 + qu];
        }
    }
    __syncthreads();

    for (int strip = s0; strip < nstrips; strip += sstep) {
        // max in fp32, pack pairs, one b128 slot write per t
        #pragma unroll
        for (int t = 0; t < 4; ++t) {
            float m0 = fmaxf(bf2f((unsigned short)cv[t][0]), bf2f((unsigned short)pv[t][0]));
            float m1 = fmaxf(bf2f((unsigned short)cv[t][1]), bf2f((unsigned short)pv[t][1]));
            float m2 = fmaxf(bf2f((unsigned short)cv[t][2]), bf2f((unsigned short)pv[t][2]));
            float m3 = fmaxf(bf2f((unsigned short)cv[t][3]), bf2f((unsigned short)pv[t][3]));
            float m4 = fmaxf(bf2f((unsigned short)cv[t][4]), bf2f((unsigned short)pv[t][4]));
            float m5 = fmaxf(bf2f((unsigned short)cv[t][5]), bf2f((unsigned short)pv[t][5]));
            float m6 = fmaxf(bf2f((unsigned short)cv[t][6]), bf2f((unsigned short)pv[t][6]));
            float m7 = fmaxf(bf2f((unsigned short)cv[t][7]), bf2f((unsigned short)pv[t][7]));
            uint4 u;
            u.x = pkbf(m0, m1); u.y = pkbf(m2, m3);
            u.z = pkbf(m4, m5); u.w = pkbf(m6, m7);
            *(uint4*)&myF[slotAddr(lnm, t * 4 + qu)] = u;
        }

        // prefetch next strip's rows (pidx already in prn), pidx two ahead
        int sn = strip + sstep;
        if (sn < nstrips) {
            #pragma unroll
            for (int t = 0; t < 4; ++t) {
                int e = sn * 16 + t * 4 + qu;
                int crow = e + (int)((unsigned)e / 4095u);
                cv[t] = *(const short8*)(h2 + (size_t)crow * NF + lnm * 8);
                pv[t] = *(const short8*)(h2 + (size_t)prn[t] * NF + lnm * 8);
            }
            int sn2 = sn + sstep;
            if (sn2 < nstrips) {
                #pragma unroll
                for (int t = 0; t < 4; ++t) prn[t] = pidx[sn2 * 16 + t * 4 + qu];
            }
        }

        // MFMA + LN/ELU + dot(Wr2)
        float4v acc[8];
        #pragma unroll
        for (int c = 0; c < 8; ++c) acc[c] = (float4v){0.f, 0.f, 0.f, 0.f};
        #pragma unroll
        for (int s = 0; s < 4; ++s) {
            short8 af = *(const short8*)&myF[slotAddr(s * 4 + qu, lnm)];
            #pragma unroll
            for (int c = 0; c < 8; ++c) {
                short8 bfv = *(const short8*)&WFr[((c * 4 + s) * 64 + lane) * 8];
                acc[c] = __builtin_amdgcn_mfma_f32_16x16x32_bf16(af, bfv, acc[c], 0, 0, 0);
            }
        }
        ln_elu(acc, PIf, lnm);

        #pragma unroll
        for (int r = 0; r < 4; ++r) {
            float t2 = 0.f;
            #pragma unroll
            for (int c = 0; c < 8; ++c) t2 += acc[c][r] * w2c[c];
            t2 = red16(t2);
            if (lnm == 0) rout[strip * 16 + qu * 4 + r] = t2 + br2v;
        }
    }
}

__global__ __launch_bounds__(1024)
void lse_kernel(const float* __restrict__ r, float* __restrict__ out)
{
    __shared__ float red[1024];
    const int b = blockIdx.x;
    const float* rb = r + (size_t)b * 4095;

    float mx = -1e30f;
    for (int i = threadIdx.x; i < 4095; i += 1024) mx = fmaxf(mx, rb[i]);
    red[threadIdx.x] = mx;
    __syncthreads();
    for (int s = 512; s > 0; s >>= 1) {
        if (threadIdx.x < s) red[threadIdx.x] = fmaxf(red[threadIdx.x], red[threadIdx.x + s]);
        __syncthreads();
    }
    mx = red[0];
    __syncthreads();

    float sum = 0.f;
    for (int i = threadIdx.x; i < 4095; i += 1024) sum += __expf(rb[i] - mx);
    red[threadIdx.x] = sum;
    __syncthreads();
    for (int s = 512; s > 0; s >>= 1) {
        if (threadIdx.x < s) red[threadIdx.x] += red[threadIdx.x + s];
        __syncthreads();
    }
    float lse = mx + __logf(red[0]);

    for (int i = threadIdx.x; i < 4095; i += 1024)
        out[(size_t)b * 4095 + i] = rb[i] - lse;
}

extern "C" void kernel_launch(void* const* d_in, const int* in_sizes, int n_in,
                              void* d_out, int out_size, void* d_ws, size_t ws_size,
                              hipStream_t stream)
{
    const float* x    = (const float*)d_in[0];
    const int*   pidx = (const int*)d_in[1];
    const float* W1   = (const float*)d_in[2];
    const float* b1   = (const float*)d_in[3];
    const float* g1   = (const float*)d_in[4];
    const float* be1  = (const float*)d_in[5];
    const float* W2   = (const float*)d_in[6];
    const float* b2   = (const float*)d_in[7];
    const float* g2   = (const float*)d_in[8];
    const float* be2  = (const float*)d_in[9];
    const float* Wr1  = (const float*)d_in[10];
    const float* br1  = (const float*)d_in[11];
    const float* gr1  = (const float*)d_in[12];
    const float* ber1 = (const float*)d_in[13];
    const float* Wr2  = (const float*)d_in[14];
    const float* br2  = (const float*)d_in[15];
    float* out = (float*)d_out;

    // workspace: h2 (bf16, 64 MiB, permuted feature layout) | rbuf (fp32)
    unsigned short* h2 = (unsigned short*)d_ws;
    float* rbuf = (float*)(h2 + (size_t)MROWS * NF);

    fused12_kernel<<<256, 512, 0, stream>>>(x, W1, b1, g1, be1,
                                            W2, b2, g2, be2, h2);
    edge_kernel<<<256, 512, 0, stream>>>(h2, pidx, Wr1, br1, gr1, ber1,
                                         Wr2, br2, rbuf);
    lse_kernel<<<BATCH, 1024, 0, stream>>>(rbuf, out);
}